// Round 1
// baseline (1087.127 us; speedup 1.0000x reference)
//
#include <hip/hip_runtime.h>
#include <hip/hip_bf16.h>
#include <math.h>

// Problem constants
#define BB 2
#define TT 1024
#define CC 2048
#define NH 16
#define NKV 4
#define HD 128
#define MROWS (BB * TT)      // 2048
#define KVC (NKV * HD)       // 512

// ---------------------------------------------------------------------------
// Tiled fp32 GEMM: C[M,N] = A[M,K] @ B[K,N].  64x64 tile, BK=16, 256 threads,
// each thread computes a 4x4 register tile.  M,N multiples of 64, K of 16.
// ---------------------------------------------------------------------------
__global__ __launch_bounds__(256) void gemm64(const float* __restrict__ A,
                                              const float* __restrict__ Bm,
                                              float* __restrict__ Cm,
                                              int Mm, int Nn, int Kk) {
    __shared__ __align__(16) float As[16][72];  // transposed: As[k][row]
    __shared__ __align__(16) float Bs[16][72];  // Bs[k][col]

    const int t  = threadIdx.x;
    const int tx = t & 15;        // output col group
    const int ty = t >> 4;        // output row group
    const int bx = blockIdx.x, by = blockIdx.y;

    // global->LDS load mapping
    const int ar  = t >> 2,  ac4 = t & 3;    // A: row 0..63, k-chunk 0..3
    const int brr = t >> 4,  bc4 = t & 15;   // B: k-row 0..15, col-chunk 0..15

    const float* aptr = A  + (size_t)(by * 64 + ar) * Kk + ac4 * 4;
    const float* bptr = Bm + (size_t)brr * Nn + bx * 64 + bc4 * 4;

    float acc[4][4];
#pragma unroll
    for (int i = 0; i < 4; ++i)
#pragma unroll
        for (int j = 0; j < 4; ++j) acc[i][j] = 0.f;

    for (int k0 = 0; k0 < Kk; k0 += 16) {
        float4 av = *(const float4*)(aptr + k0);
        float4 bv = *(const float4*)(bptr + (size_t)k0 * Nn);
        As[ac4 * 4 + 0][ar] = av.x;
        As[ac4 * 4 + 1][ar] = av.y;
        As[ac4 * 4 + 2][ar] = av.z;
        As[ac4 * 4 + 3][ar] = av.w;
        *(float4*)&Bs[brr][bc4 * 4] = bv;
        __syncthreads();
#pragma unroll
        for (int kk = 0; kk < 16; ++kk) {
            float4 a4 = *(const float4*)&As[kk][ty * 4];
            float4 b4 = *(const float4*)&Bs[kk][tx * 4];
            float ai[4] = {a4.x, a4.y, a4.z, a4.w};
            float bj[4] = {b4.x, b4.y, b4.z, b4.w};
#pragma unroll
            for (int i = 0; i < 4; ++i)
#pragma unroll
                for (int j = 0; j < 4; ++j) acc[i][j] += ai[i] * bj[j];
        }
        __syncthreads();
    }

#pragma unroll
    for (int i = 0; i < 4; ++i) {
        float4 cv = make_float4(acc[i][0], acc[i][1], acc[i][2], acc[i][3]);
        *(float4*)&Cm[(size_t)(by * 64 + ty * 4 + i) * Nn + bx * 64 + tx * 4] = cv;
    }
}

// ---------------------------------------------------------------------------
// RoPE: interleaved-pair rotation, in place. x viewed as (MROWS, nheads, HD).
// pair p uses angles[t_pos][p], t_pos = row % T.
// ---------------------------------------------------------------------------
__global__ void rope_kernel(float* __restrict__ x, const float* __restrict__ angles,
                            int nheads, int total) {
    int idx = blockIdx.x * 256 + threadIdx.x;
    if (idx >= total) return;
    int p    = idx & (HD / 2 - 1);          // 0..63
    int rest = idx >> 6;
    int h    = rest % nheads;
    int m    = rest / nheads;
    int tpos = m & (TT - 1);
    float ang = angles[tpos * (HD / 2) + p];
    float c, s;
    __sincosf(ang, &s, &c);
    float* base = x + ((size_t)m * nheads + h) * HD + 2 * p;
    float2 xv = *(float2*)base;
    float2 rv = make_float2(c * xv.x - s * xv.y, s * xv.x + c * xv.y);
    *(float2*)base = rv;
}

// ---------------------------------------------------------------------------
// Flash-style attention with swapped roles:
//   out[b,h,i,:] = sum_{j<=i} softmax_j( K[b,hk,i,:] . Q[b,h,j,:] ) * V[b,hk,j,:]
// One block per (i_tile of 64 rows, b*NH+h).  256 threads:
//   thread t -> row i = t>>2, lane-in-row tm = t&3.
// ---------------------------------------------------------------------------
#define AT_BR 64
#define AT_BC 32
#define AT_PAD 132   // 128 + 4: float4-aligned, breaks power-of-2 bank stride

__global__ __launch_bounds__(256) void attn_kernel(const float* __restrict__ q,
                                                   const float* __restrict__ k,
                                                   const float* __restrict__ v,
                                                   float* __restrict__ attn) {
    __shared__ __align__(16) float Kt[AT_BR][AT_PAD];
    __shared__ __align__(16) float QV[AT_BC][AT_PAD];
    __shared__ float Pl[AT_BR][AT_BC + 1];

    const int it = blockIdx.x;
    const int bh = blockIdx.y;
    const int b  = bh >> 4;       // / NH
    const int h  = bh & 15;       // % NH
    const int hk = h & (NKV - 1); // h % NKV
    const int t  = threadIdx.x;
    const int i  = t >> 2;
    const int tm = t & 3;
    const int i0 = it * AT_BR;
    const int gi = i0 + i;

    // Load this block's K rows (queries-role): k[b, i0+r, hk, :]
#pragma unroll
    for (int e = 0; e < 8; ++e) {
        int idx = t + e * 256;
        int r = idx >> 5, c4 = idx & 31;
        const float* src = k + (size_t)(b * TT + i0 + r) * KVC + hk * HD + c4 * 4;
        *(float4*)&Kt[r][c4 * 4] = *(const float4*)src;
    }

    float4 o[8];
#pragma unroll
    for (int cc = 0; cc < 8; ++cc) o[cc] = make_float4(0.f, 0.f, 0.f, 0.f);
    float mrun = -INFINITY, lrun = 0.f;

    const int njt = 2 * it + 2;   // tiles 0 .. 2*it+1 cover j <= i0+63
    for (int jt = 0; jt < njt; ++jt) {
        const int j0 = jt * AT_BC;
        __syncthreads();          // prev PV done with QV
        // load Q tile: q[b, j0+r, h, :]
#pragma unroll
        for (int e = 0; e < 4; ++e) {
            int idx = t + e * 256;
            int r = idx >> 5, c4 = idx & 31;
            const float* src = q + (size_t)(b * TT + j0 + r) * CC + h * HD + c4 * 4;
            *(float4*)&QV[r][c4 * 4] = *(const float4*)src;
        }
        __syncthreads();
        // S[i][j] = Kt[i,:] . Qt[j,:], thread's j = tm + 4*jj
        float acc[8];
#pragma unroll
        for (int jj = 0; jj < 8; ++jj) acc[jj] = 0.f;
        for (int d4 = 0; d4 < 32; ++d4) {
            float4 kv = *(const float4*)&Kt[i][d4 * 4];
#pragma unroll
            for (int jj = 0; jj < 8; ++jj) {
                float4 qv = *(const float4*)&QV[tm + 4 * jj][d4 * 4];
                acc[jj] += kv.x * qv.x + kv.y * qv.y + kv.z * qv.z + kv.w * qv.w;
            }
        }
        // causal mask (j <= i) + online softmax
        float tmax = -INFINITY;
#pragma unroll
        for (int jj = 0; jj < 8; ++jj) {
            int gj = j0 + tm + 4 * jj;
            acc[jj] = (gj <= gi) ? acc[jj] : -INFINITY;
            tmax = fmaxf(tmax, acc[jj]);
        }
        tmax = fmaxf(tmax, __shfl_xor(tmax, 1, 4));
        tmax = fmaxf(tmax, __shfl_xor(tmax, 2, 4));
        float mnew  = fmaxf(mrun, tmax);
        float alpha = __expf(mrun - mnew);   // mrun=-inf only before tile 0, mnew finite there
        float psum = 0.f;
#pragma unroll
        for (int jj = 0; jj < 8; ++jj) {
            float p = __expf(acc[jj] - mnew);
            psum += p;
            Pl[i][tm + 4 * jj] = p;
        }
        psum += __shfl_xor(psum, 1, 4);
        psum += __shfl_xor(psum, 2, 4);
        lrun = lrun * alpha + psum;
        mrun = mnew;
#pragma unroll
        for (int cc = 0; cc < 8; ++cc) {
            o[cc].x *= alpha; o[cc].y *= alpha; o[cc].z *= alpha; o[cc].w *= alpha;
        }
        __syncthreads();          // everyone done reading Qt + writing Pl
        // load V tile over QV: v[b, j0+r, hk, :]
#pragma unroll
        for (int e = 0; e < 4; ++e) {
            int idx = t + e * 256;
            int r = idx >> 5, c4 = idx & 31;
            const float* src = v + (size_t)(b * TT + j0 + r) * KVC + hk * HD + c4 * 4;
            *(float4*)&QV[r][c4 * 4] = *(const float4*)src;
        }
        __syncthreads();
        // O[i, :] += P[i, j] * V[j, :]; thread owns chunks c = tm + 4*cc
        for (int j = 0; j < AT_BC; ++j) {
            float p = Pl[i][j];
#pragma unroll
            for (int cc = 0; cc < 8; ++cc) {
                float4 vv = *(const float4*)&QV[j][(tm + 4 * cc) * 4];
                o[cc].x += p * vv.x; o[cc].y += p * vv.y;
                o[cc].z += p * vv.z; o[cc].w += p * vv.w;
            }
        }
    }

    const float inv = 1.f / lrun;
    float* dst = attn + (size_t)(b * TT + gi) * CC + h * HD;
#pragma unroll
    for (int cc = 0; cc < 8; ++cc) {
        float4 ov = o[cc];
        ov.x *= inv; ov.y *= inv; ov.z *= inv; ov.w *= inv;
        *(float4*)&dst[(tm + 4 * cc) * 4] = ov;
    }
}

// ---------------------------------------------------------------------------
extern "C" void kernel_launch(void* const* d_in, const int* in_sizes, int n_in,
                              void* d_out, int out_size, void* d_ws, size_t ws_size,
                              hipStream_t stream) {
    const float* x      = (const float*)d_in[0];
    const float* angles = (const float*)d_in[1];
    const float* wq     = (const float*)d_in[2];
    const float* wk     = (const float*)d_in[3];
    const float* wv     = (const float*)d_in[4];
    const float* wo     = (const float*)d_in[5];
    float* out = (float*)d_out;

    float* q    = (float*)d_ws;                       // MROWS * CC
    float* k    = q + (size_t)MROWS * CC;             // MROWS * KVC
    float* v    = k + (size_t)MROWS * KVC;            // MROWS * KVC
    float* attn = v + (size_t)MROWS * KVC;            // MROWS * CC

    // QKV projections
    gemm64<<<dim3(CC / 64, MROWS / 64), 256, 0, stream>>>(x, wq, q, MROWS, CC, CC);
    gemm64<<<dim3(KVC / 64, MROWS / 64), 256, 0, stream>>>(x, wk, k, MROWS, KVC, CC);
    gemm64<<<dim3(KVC / 64, MROWS / 64), 256, 0, stream>>>(x, wv, v, MROWS, KVC, CC);

    // RoPE on q (16 heads) and k (4 heads)
    {
        int total_q = MROWS * NH * (HD / 2);
        rope_kernel<<<(total_q + 255) / 256, 256, 0, stream>>>(q, angles, NH, total_q);
        int total_k = MROWS * NKV * (HD / 2);
        rope_kernel<<<(total_k + 255) / 256, 256, 0, stream>>>(k, angles, NKV, total_k);
    }

    // Attention
    attn_kernel<<<dim3(TT / AT_BR, BB * NH), 256, 0, stream>>>(q, k, v, attn);

    // Output projection
    gemm64<<<dim3(CC / 64, MROWS / 64), 256, 0, stream>>>(attn, wo, out, MROWS, CC, CC);
}

// Round 3
// 205.020 us; speedup vs baseline: 5.3025x; 5.3025x over previous
//
#include <hip/hip_runtime.h>
#include <hip/hip_bf16.h>
#include <math.h>

#define BB 2
#define TT 1024
#define CC 2048
#define NH 16
#define NKV 4
#define HD 128
#define MROWS (BB * TT)        // 2048
#define QKVN 3072              // 2048 q + 512 k + 512 v
#define KOFF 2048
#define VOFF 2560

typedef unsigned short u16;
typedef unsigned int   u32;
typedef _Float16 f16;
typedef _Float16 f16x8 __attribute__((ext_vector_type(8)));
typedef short    s16x8 __attribute__((ext_vector_type(8)));
typedef float    f32x4 __attribute__((ext_vector_type(4)));

__device__ __forceinline__ u16 f2h(float f) {
    union { f16 h; u16 u; } x; x.h = (f16)f; return x.u;
}
__device__ __forceinline__ float h2f(u16 u) {
    union { u16 u; f16 h; } x; x.u = u; return (float)x.h;
}

#define GLDS(gp, lp) __builtin_amdgcn_global_load_lds( \
    (const __attribute__((address_space(1))) u32*)(gp), \
    (__attribute__((address_space(3))) u32*)(lp), 16, 0, 0)

// ---------------------------------------------------------------------------
// x fp32 -> fp16 (elementwise, float4 -> 4xfp16)
// ---------------------------------------------------------------------------
__global__ void conv_x(const float* __restrict__ src, u16* __restrict__ dst, int n4) {
    int i = blockIdx.x * 256 + threadIdx.x;
    if (i >= n4) return;
    float4 v = ((const float4*)src)[i];
    ushort4 o;
    o.x = f2h(v.x); o.y = f2h(v.y); o.z = f2h(v.z); o.w = f2h(v.w);
    ((ushort4*)dst)[i] = o;
}

// ---------------------------------------------------------------------------
// Transpose-convert: Wt[row_off + n][k] = src[k][n]  (K=2048 fixed), fp16 out
// ---------------------------------------------------------------------------
__global__ __launch_bounds__(256) void conv_wT(const float* __restrict__ src,
                                               u16* __restrict__ Wt,
                                               int Nsrc, int row_off) {
    __shared__ float tile[32][33];
    const int k0 = blockIdx.x * 32;
    const int n0 = blockIdx.y * 32;
    const int t = threadIdx.x;
    const int r = t >> 3, c4 = (t & 7) * 4;
    float4 v = *(const float4*)&src[(size_t)(k0 + r) * Nsrc + n0 + c4];
    tile[r][c4 + 0] = v.x; tile[r][c4 + 1] = v.y;
    tile[r][c4 + 2] = v.z; tile[r][c4 + 3] = v.w;
    __syncthreads();
    ushort4 o;
    o.x = f2h(tile[c4 + 0][r]); o.y = f2h(tile[c4 + 1][r]);
    o.z = f2h(tile[c4 + 2][r]); o.w = f2h(tile[c4 + 3][r]);
    *(ushort4*)&Wt[(size_t)(row_off + n0 + r) * 2048 + k0 + c4] = o;
}

// ---------------------------------------------------------------------------
// RoPE in-place on fp16 qkv buffer (rows MROWS, stride QKVN).
// idx < nq: q pairs (col = h*128 + 2p); else: k pairs (col = KOFF + h*128 + 2p)
// Precise sinf/cosf: angles go up to ~1023 rad, fast versions lose accuracy.
// ---------------------------------------------------------------------------
__global__ void rope_hf(u16* __restrict__ qkv, const float* __restrict__ angles,
                        int nq, int ntot) {
    int idx = blockIdx.x * 256 + threadIdx.x;
    if (idx >= ntot) return;
    int p, col, m;
    if (idx < nq) {
        p = idx & 63; int rest = idx >> 6;
        int h = rest & 15; m = rest >> 4;
        col = h * 128 + 2 * p;
    } else {
        int j = idx - nq; p = j & 63; int rest = j >> 6;
        int h = rest & 3; m = rest >> 2;
        col = KOFF + h * 128 + 2 * p;
    }
    int tpos = m & (TT - 1);
    float ang = angles[tpos * 64 + p];
    float s = sinf(ang), c = cosf(ang);
    u32* ptr = (u32*)(qkv + (size_t)m * QKVN + col);
    u32 pr = *ptr;
    float x0 = h2f((u16)(pr & 0xFFFF)), x1 = h2f((u16)(pr >> 16));
    float r0 = c * x0 - s * x1, r1 = s * x0 + c * x1;
    *ptr = (u32)f2h(r0) | ((u32)f2h(r1) << 16);
}

// ---------------------------------------------------------------------------
// fp16 MFMA GEMM: C[M,N] = A[M,K] @ Bt[N,K]^T.  128x128 tile, BK=32,
// 256 threads (4 waves, 2x2 of 64x64), global_load_lds(16B), XOR-swizzled LDS.
// OUTB=1 -> fp16 out, else fp32.
// ---------------------------------------------------------------------------
template <int OUTB>
__global__ __launch_bounds__(256) void gemm_f16(const u16* __restrict__ A,
                                                const u16* __restrict__ Bt,
                                                float* __restrict__ Cf,
                                                u16* __restrict__ Cb,
                                                int M, int N, int K) {
    __shared__ __align__(16) u16 As[128 * 32];
    __shared__ __align__(16) u16 Bs[128 * 32];
    const int t = threadIdx.x;
    const int l = t & 63;
    const int w = t >> 6;
    const int row0 = blockIdx.y * 128;
    const int col0 = blockIdx.x * 128;
    const int wr = w >> 1, wc = w & 1;

    const int srow0  = 16 * (2 * w) + (l >> 2);
    const int schunk = (l & 3) ^ ((l >> 2) & 3);
    const u16* aP0 = A  + (size_t)(row0 + srow0)      * K + schunk * 8;
    const u16* aP1 = A  + (size_t)(row0 + srow0 + 16) * K + schunk * 8;
    const u16* bP0 = Bt + (size_t)(col0 + srow0)      * K + schunk * 8;
    const u16* bP1 = Bt + (size_t)(col0 + srow0 + 16) * K + schunk * 8;
    u16* asl0 = As + (2 * w + 0) * 512;
    u16* asl1 = As + (2 * w + 1) * 512;
    u16* bsl0 = Bs + (2 * w + 0) * 512;
    u16* bsl1 = Bs + (2 * w + 1) * 512;

    f32x4 acc[4][4] = {};

    const int ar = wr * 64 + (l & 15);
    const int br = wc * 64 + (l & 15);
    const int lg = l >> 4;

    for (int k0 = 0; k0 < K; k0 += 32) {
        __syncthreads();
        GLDS(aP0 + k0, asl0);
        GLDS(aP1 + k0, asl1);
        GLDS(bP0 + k0, bsl0);
        GLDS(bP1 + k0, bsl1);
        __syncthreads();
        f16x8 af[4], bfr[4];
#pragma unroll
        for (int m = 0; m < 4; ++m) {
            int row = ar + 16 * m;
            af[m]  = *(const f16x8*)&As[row * 32 + ((lg ^ (row & 3)) * 8)];
            int col = br + 16 * m;
            bfr[m] = *(const f16x8*)&Bs[col * 32 + ((lg ^ (col & 3)) * 8)];
        }
#pragma unroll
        for (int m = 0; m < 4; ++m)
#pragma unroll
            for (int n = 0; n < 4; ++n)
                acc[m][n] = __builtin_amdgcn_mfma_f32_16x16x32_f16(
                    af[m], bfr[n], acc[m][n], 0, 0, 0);
    }

    const int orow = row0 + wr * 64 + lg * 4;
    const int ocol = col0 + wc * 64 + (l & 15);
#pragma unroll
    for (int m = 0; m < 4; ++m)
#pragma unroll
        for (int n = 0; n < 4; ++n)
#pragma unroll
            for (int r = 0; r < 4; ++r) {
                size_t off = (size_t)(orow + 16 * m + r) * N + ocol + 16 * n;
                if (OUTB) Cb[off] = f2h(acc[m][n][r]);
                else      Cf[off] = acc[m][n][r];
            }
}

// ---------------------------------------------------------------------------
// MFMA flash attention, swapped roles (K rows are MFMA M; softmax over q-cols).
// Block: 64 i-rows (4 waves x 16), j-tiles of 32. K-frags in registers.
// ---------------------------------------------------------------------------
__global__ __launch_bounds__(256) void attn_mfma(const u16* __restrict__ qkv,
                                                 u16* __restrict__ attnb) {
    __shared__ __align__(16) u16 Qs[32 * 136];   // pad 136: 2-way free
    __shared__ __align__(16) u16 Vt[128 * 40];   // V^T, pad 40
    __shared__ __align__(16) u16 Ps[4 * 16 * 40];

    const int t = threadIdx.x, l = t & 63, w = t >> 6;
    const int it = (TT / 64 - 1) - blockIdx.x;   // big tiles first
    const int bh = blockIdx.y;
    const int b = bh >> 4, h = bh & 15, hk = h & 3;
    const int i0 = it * 64;
    const int iw = i0 + w * 16;
    const int lg = l >> 4, ll = l & 15;

    f16x8 kf[4];
    {
        const u16* kp = qkv + (size_t)(b * TT + iw + ll) * QKVN + KOFF + hk * 128 + lg * 8;
#pragma unroll
        for (int c = 0; c < 4; ++c) kf[c] = *(const f16x8*)(kp + 32 * c);
    }

    f32x4 o[8] = {};
    float mrun[4] = {-1e30f, -1e30f, -1e30f, -1e30f};
    float lrun[4] = {0.f, 0.f, 0.f, 0.f};

    const int njt = 2 * it + 2;
    for (int jt = 0; jt < njt; ++jt) {
        const int j0 = jt * 32;
        __syncthreads();
        // stage Q tile (32 x 128)
#pragma unroll
        for (int e = 0; e < 2; ++e) {
            int idx = t + e * 256;
            int r = idx >> 4, c8 = idx & 15;
            s16x8 v = *(const s16x8*)(qkv + (size_t)(b * TT + j0 + r) * QKVN + h * 128 + c8 * 8);
            *(s16x8*)&Qs[r * 136 + c8 * 8] = v;
        }
        // stage V^T (128 x 32): thread packs 2 j's per u32
        {
            int jp = t & 15, c8 = t >> 4;
            const u16* v0 = qkv + (size_t)(b * TT + j0 + 2 * jp) * QKVN + VOFF + hk * 128 + c8 * 8;
            s16x8 va = *(const s16x8*)v0;
            s16x8 vb = *(const s16x8*)(v0 + QKVN);
#pragma unroll
            for (int u = 0; u < 8; ++u) {
                u32 pk = (u32)(u16)va[u] | ((u32)(u16)vb[u] << 16);
                *(u32*)&Vt[(c8 * 8 + u) * 40 + 2 * jp] = pk;
            }
        }
        __syncthreads();

        // S = K_i . Q_j^T : 8 MFMAs (4 k-chunks x 2 j-col-frags)
        f32x4 s[2] = {};
#pragma unroll
        for (int kc = 0; kc < 4; ++kc) {
#pragma unroll
            for (int n = 0; n < 2; ++n) {
                f16x8 qf = *(const f16x8*)&Qs[(16 * n + ll) * 136 + lg * 8 + 32 * kc];
                s[n] = __builtin_amdgcn_mfma_f32_16x16x32_f16(kf[kc], qf, s[n], 0, 0, 0);
            }
        }

        // mask + online softmax (rows = i, cols = j across 16 lanes x 2 frags)
        const int gi = iw + lg * 4;
        const int gj = j0 + ll;
        float p[2][4];
#pragma unroll
        for (int r = 0; r < 4; ++r) {
            float s0 = (gj      <= gi + r) ? s[0][r] : -1e30f;
            float s1 = (gj + 16 <= gi + r) ? s[1][r] : -1e30f;
            float tm = fmaxf(s0, s1);
            tm = fmaxf(tm, __shfl_xor(tm, 1, 16));
            tm = fmaxf(tm, __shfl_xor(tm, 2, 16));
            tm = fmaxf(tm, __shfl_xor(tm, 4, 16));
            tm = fmaxf(tm, __shfl_xor(tm, 8, 16));
            float mnew = fmaxf(mrun[r], tm);
            float alpha = __expf(mrun[r] - mnew);
            float p0 = __expf(s0 - mnew), p1 = __expf(s1 - mnew);
            float ps = p0 + p1;
            ps += __shfl_xor(ps, 1, 16);
            ps += __shfl_xor(ps, 2, 16);
            ps += __shfl_xor(ps, 4, 16);
            ps += __shfl_xor(ps, 8, 16);
            lrun[r] = lrun[r] * alpha + ps;
            mrun[r] = mnew;
            p[0][r] = p0; p[1][r] = p1;
#pragma unroll
            for (int n = 0; n < 8; ++n) o[n][r] *= alpha;
        }

        // P -> per-wave LDS (D-layout scatter), read back in A-layout
        u16* pw = Ps + w * (16 * 40);
#pragma unroll
        for (int n = 0; n < 2; ++n)
#pragma unroll
            for (int r = 0; r < 4; ++r)
                pw[(lg * 4 + r) * 40 + ll + 16 * n] = f2h(p[n][r]);

        f16x8 pa = *(const f16x8*)&pw[ll * 40 + lg * 8];
#pragma unroll
        for (int n = 0; n < 8; ++n) {
            f16x8 vf = *(const f16x8*)&Vt[(16 * n + ll) * 40 + lg * 8];
            o[n] = __builtin_amdgcn_mfma_f32_16x16x32_f16(pa, vf, o[n], 0, 0, 0);
        }
    }

    // epilogue: attnb[b*T + i][h*128 + d], fp16
    u16* dst = attnb + (size_t)(b * TT + iw + lg * 4) * CC + h * 128 + ll;
#pragma unroll
    for (int r = 0; r < 4; ++r) {
        float inv = 1.0f / lrun[r];
#pragma unroll
        for (int n = 0; n < 8; ++n)
            dst[(size_t)r * CC + 16 * n] = f2h(o[n][r] * inv);
    }
}

// ---------------------------------------------------------------------------
extern "C" void kernel_launch(void* const* d_in, const int* in_sizes, int n_in,
                              void* d_out, int out_size, void* d_ws, size_t ws_size,
                              hipStream_t stream) {
    const float* x      = (const float*)d_in[0];
    const float* angles = (const float*)d_in[1];
    const float* wq     = (const float*)d_in[2];
    const float* wk     = (const float*)d_in[3];
    const float* wv     = (const float*)d_in[4];
    const float* wo     = (const float*)d_in[5];
    float* out = (float*)d_out;

    char* ws = (char*)d_ws;
    u16* Wt1   = (u16*)ws;                                   // 3072*2048 f16
    u16* xb    = (u16*)(ws + (size_t)QKVN * 2048 * 2);       // 2048*2048 f16 (reused as attnb)
    u16* qkvb  = (u16*)(ws + (size_t)QKVN * 2048 * 2 + (size_t)2048 * 2048 * 2);
    u16* attnb = xb;

    // 1. x -> fp16
    conv_x<<<(MROWS * CC / 4 + 255) / 256, 256, 0, stream>>>(x, xb, MROWS * CC / 4);
    // 2. weights -> Wt1 = [Wq;Wk;Wv]^T (3072 x 2048) fp16
    conv_wT<<<dim3(64, 64), 256, 0, stream>>>(wq, Wt1, CC,  0);
    conv_wT<<<dim3(64, 16), 256, 0, stream>>>(wk, Wt1, 512, 2048);
    conv_wT<<<dim3(64, 16), 256, 0, stream>>>(wv, Wt1, 512, 2560);
    // 3. fused QKV projection -> qkvb (fp16)
    gemm_f16<1><<<dim3(QKVN / 128, MROWS / 128), 256, 0, stream>>>(
        xb, Wt1, (float*)nullptr, qkvb, MROWS, QKVN, CC);
    // 4. RoPE in place on q and k regions
    {
        int nq = MROWS * NH * 64, nk = MROWS * NKV * 64;
        rope_hf<<<(nq + nk + 255) / 256, 256, 0, stream>>>(qkvb, angles, nq, nq + nk);
    }
    // 5. attention -> attnb (fp16)
    attn_mfma<<<dim3(TT / 64, BB * NH), 256, 0, stream>>>(qkvb, attnb);
    // 6. Wo^T -> Wt1 (reuse), then output projection (fp32 out)
    conv_wT<<<dim3(64, 64), 256, 0, stream>>>(wo, Wt1, CC, 0);
    gemm_f16<0><<<dim3(CC / 128, MROWS / 128), 256, 0, stream>>>(
        attnb, Wt1, out, (u16*)nullptr, MROWS, CC, CC);
}

// Round 4
// 167.696 us; speedup vs baseline: 6.4827x; 1.2226x over previous
//
#include <hip/hip_runtime.h>
#include <hip/hip_bf16.h>
#include <math.h>

#define BB 2
#define TT 1024
#define CC 2048
#define NH 16
#define NKV 4
#define HD 128
#define MROWS 2048
#define QKVN 3072              // 2048 q + 512 k + 512 v
#define KOFF 2048
#define VOFF 2560

typedef unsigned short u16;
typedef unsigned int   u32;
typedef _Float16 f16;
typedef _Float16 f16x8 __attribute__((ext_vector_type(8)));
typedef float    f32x4 __attribute__((ext_vector_type(4)));

__device__ __forceinline__ u16 f2h(float f) {
    union { f16 h; u16 u; } x; x.h = (f16)f; return x.u;
}
__device__ __forceinline__ float h2f(u16 u) {
    union { u16 u; f16 h; } x; x.u = u; return (float)x.h;
}

#define GLDS(gp, lp) __builtin_amdgcn_global_load_lds( \
    (const __attribute__((address_space(1))) u32*)(gp), \
    (__attribute__((address_space(3))) u32*)(lp), 16, 0, 0)

// ---------------------------------------------------------------------------
// x fp32 -> fp16
// ---------------------------------------------------------------------------
__global__ void conv_x(const float* __restrict__ src, u16* __restrict__ dst, int n4) {
    int i = blockIdx.x * 256 + threadIdx.x;
    if (i >= n4) return;
    float4 v = ((const float4*)src)[i];
    ushort4 o;
    o.x = f2h(v.x); o.y = f2h(v.y); o.z = f2h(v.z); o.w = f2h(v.w);
    ((ushort4*)dst)[i] = o;
}

// ---------------------------------------------------------------------------
// Transpose-convert: Wt[row_off + n][k] = src[k][n]  (K=2048 fixed), fp16 out
// ---------------------------------------------------------------------------
__global__ __launch_bounds__(256) void conv_wT(const float* __restrict__ src,
                                               u16* __restrict__ Wt,
                                               int Nsrc, int row_off) {
    __shared__ float tile[32][33];
    const int k0 = blockIdx.x * 32;
    const int n0 = blockIdx.y * 32;
    const int t = threadIdx.x;
    const int r = t >> 3, c4 = (t & 7) * 4;
    float4 v = *(const float4*)&src[(size_t)(k0 + r) * Nsrc + n0 + c4];
    tile[r][c4 + 0] = v.x; tile[r][c4 + 1] = v.y;
    tile[r][c4 + 2] = v.z; tile[r][c4 + 3] = v.w;
    __syncthreads();
    ushort4 o;
    o.x = f2h(tile[c4 + 0][r]); o.y = f2h(tile[c4 + 1][r]);
    o.z = f2h(tile[c4 + 2][r]); o.w = f2h(tile[c4 + 3][r]);
    *(ushort4*)&Wt[(size_t)(row_off + n0 + r) * 2048 + k0 + c4] = o;
}

// ---------------------------------------------------------------------------
// RoPE + split-K reduce: qkv[m][col] = rope(p0[m][col] + p1[m][col]) for q,k.
// ---------------------------------------------------------------------------
__global__ void rope_red(const u16* __restrict__ pp, u16* __restrict__ qkv,
                         const float* __restrict__ angles, int nq, int ntot) {
    const size_t PSZ = (size_t)MROWS * QKVN;
    int idx = blockIdx.x * 256 + threadIdx.x;
    if (idx >= ntot) return;
    int p, col, m;
    if (idx < nq) {
        p = idx & 63; int rest = idx >> 6;
        int h = rest & 15; m = rest >> 4;
        col = h * 128 + 2 * p;
    } else {
        int j = idx - nq; p = j & 63; int rest = j >> 6;
        int h = rest & 3; m = rest >> 2;
        col = KOFF + h * 128 + 2 * p;
    }
    size_t off = (size_t)m * QKVN + col;
    u32 a = *(const u32*)(pp + off);
    u32 b = *(const u32*)(pp + PSZ + off);
    float x0 = h2f((u16)(a & 0xFFFF)) + h2f((u16)(b & 0xFFFF));
    float x1 = h2f((u16)(a >> 16))    + h2f((u16)(b >> 16));
    int tpos = m & (TT - 1);
    float ang = angles[tpos * 64 + p];
    float s = sinf(ang), c = cosf(ang);
    float r0 = c * x0 - s * x1, r1 = s * x0 + c * x1;
    *(u32*)(qkv + off) = (u32)f2h(r0) | ((u32)f2h(r1) << 16);
}

// ---------------------------------------------------------------------------
// V^T + split-K reduce: vtg[(b*NKV+hk)*128 + d][j] = p0.v + p1.v  (fp16)
// grid (32 j-tiles, 4 d-tiles, 8 b*hk), 256 thr, 32x32 LDS transpose.
// ---------------------------------------------------------------------------
__global__ __launch_bounds__(256) void vT_red(const u16* __restrict__ pp,
                                              u16* __restrict__ vtg) {
    const size_t PSZ = (size_t)MROWS * QKVN;
    __shared__ u16 tl[32][34];
    const int j0 = blockIdx.x * 32;
    const int d0 = blockIdx.y * 32;
    const int bhk = blockIdx.z;
    const int b = bhk >> 2, hk = bhk & 3;
    const int t = threadIdx.x;
    {
        int j_in = t >> 3, c4 = (t & 7) * 4;
        size_t off = (size_t)(b * TT + j0 + j_in) * QKVN + VOFF + hk * 128 + d0 + c4;
        ushort4 a = *(const ushort4*)(pp + off);
        ushort4 b4 = *(const ushort4*)(pp + PSZ + off);
        tl[j_in][c4 + 0] = f2h(h2f(a.x) + h2f(b4.x));
        tl[j_in][c4 + 1] = f2h(h2f(a.y) + h2f(b4.y));
        tl[j_in][c4 + 2] = f2h(h2f(a.z) + h2f(b4.z));
        tl[j_in][c4 + 3] = f2h(h2f(a.w) + h2f(b4.w));
    }
    __syncthreads();
    {
        int d_in = t >> 3, j4 = (t & 7) * 4;
        ushort4 o;
        o.x = tl[j4 + 0][d_in]; o.y = tl[j4 + 1][d_in];
        o.z = tl[j4 + 2][d_in]; o.w = tl[j4 + 3][d_in];
        *(ushort4*)&vtg[(size_t)(bhk * 128 + d0 + d_in) * 1024 + j0 + j4] = o;
    }
}

// ---------------------------------------------------------------------------
// fp16 MFMA GEMM, split-K via blockIdx.z: C_z = A[:, z*klen:(z+1)*klen] @ Bt^T.
// 128x128 tile, BK=32, 4 waves, global_load_lds(16B), XOR-swizzled LDS.
// ---------------------------------------------------------------------------
template <int OUTB>
__global__ __launch_bounds__(256) void gemm_f16(const u16* __restrict__ A,
                                                const u16* __restrict__ Bt,
                                                float* __restrict__ Cf,
                                                u16* __restrict__ Cb,
                                                int M, int N, int K, int klen) {
    __shared__ __align__(16) u16 As[128 * 32];
    __shared__ __align__(16) u16 Bs[128 * 32];
    const int t = threadIdx.x;
    const int l = t & 63;
    const int w = t >> 6;
    const int row0 = blockIdx.y * 128;
    const int col0 = blockIdx.x * 128;
    const int koff = blockIdx.z * klen;
    const int wr = w >> 1, wc = w & 1;

    const int srow0  = 16 * (2 * w) + (l >> 2);
    const int schunk = (l & 3) ^ ((l >> 2) & 3);
    const u16* aP0 = A  + (size_t)(row0 + srow0)      * K + schunk * 8;
    const u16* aP1 = A  + (size_t)(row0 + srow0 + 16) * K + schunk * 8;
    const u16* bP0 = Bt + (size_t)(col0 + srow0)      * K + schunk * 8;
    const u16* bP1 = Bt + (size_t)(col0 + srow0 + 16) * K + schunk * 8;
    u16* asl0 = As + (2 * w + 0) * 512;
    u16* asl1 = As + (2 * w + 1) * 512;
    u16* bsl0 = Bs + (2 * w + 0) * 512;
    u16* bsl1 = Bs + (2 * w + 1) * 512;

    f32x4 acc[4][4] = {};

    const int ar = wr * 64 + (l & 15);
    const int br = wc * 64 + (l & 15);
    const int lg = l >> 4;

    for (int k0 = koff; k0 < koff + klen; k0 += 32) {
        __syncthreads();
        GLDS(aP0 + k0, asl0);
        GLDS(aP1 + k0, asl1);
        GLDS(bP0 + k0, bsl0);
        GLDS(bP1 + k0, bsl1);
        __syncthreads();
        f16x8 af[4], bfr[4];
#pragma unroll
        for (int m = 0; m < 4; ++m) {
            int row = ar + 16 * m;
            af[m]  = *(const f16x8*)&As[row * 32 + ((lg ^ (row & 3)) * 8)];
            int col = br + 16 * m;
            bfr[m] = *(const f16x8*)&Bs[col * 32 + ((lg ^ (col & 3)) * 8)];
        }
#pragma unroll
        for (int m = 0; m < 4; ++m)
#pragma unroll
            for (int n = 0; n < 4; ++n)
                acc[m][n] = __builtin_amdgcn_mfma_f32_16x16x32_f16(
                    af[m], bfr[n], acc[m][n], 0, 0, 0);
    }

    const size_t zoff = (size_t)blockIdx.z * M * N;
    const int orow = row0 + wr * 64 + lg * 4;
    const int ocol = col0 + wc * 64 + (l & 15);
#pragma unroll
    for (int m = 0; m < 4; ++m)
#pragma unroll
        for (int n = 0; n < 4; ++n)
#pragma unroll
            for (int r = 0; r < 4; ++r) {
                size_t off = zoff + (size_t)(orow + 16 * m + r) * N + ocol + 16 * n;
                if (OUTB) Cb[off] = f2h(acc[m][n][r]);
                else      Cf[off] = acc[m][n][r];
            }
}

// ---------------------------------------------------------------------------
// out = p0 + p1 (fp32 elementwise)
// ---------------------------------------------------------------------------
__global__ void red_f32(const float* __restrict__ pp, float* __restrict__ out, int n4) {
    int i = blockIdx.x * 256 + threadIdx.x;
    if (i >= n4) return;
    const size_t PSZ = (size_t)MROWS * CC;
    float4 a = ((const float4*)pp)[i];
    float4 b = ((const float4*)(pp + PSZ))[i];
    ((float4*)out)[i] = make_float4(a.x + b.x, a.y + b.y, a.z + b.z, a.w + b.w);
}

// ---------------------------------------------------------------------------
// MFMA flash attention (swapped roles). Block = 64 i-rows (4 waves x 16 rows),
// j-tiles of 64. K-frags in registers; Q and V^T staged via global_load_lds
// with XOR-swizzled sources (linear LDS dest, swizzled reads). Defer-max
// rescale (thr=8); mask only on the diagonal tile.
// ---------------------------------------------------------------------------
__global__ __launch_bounds__(256) void attn_mfma(const u16* __restrict__ qkv,
                                                 const u16* __restrict__ vtg,
                                                 u16* __restrict__ attnb) {
    __shared__ __align__(16) u16 Qs[64 * 128];   // [j_loc][d], chunk-swizzled
    __shared__ __align__(16) u16 Vt[128 * 64];   // [d][j_loc], chunk-swizzled
    __shared__ __align__(16) u16 Ps[4 * 16 * 72];

    const int t = threadIdx.x, l = t & 63, w = t >> 6;
    const int it = (TT / 64 - 1) - blockIdx.x;   // big blocks first
    const int bh = blockIdx.y;
    const int b = bh >> 4, h = bh & 15, hk = h & 3;
    const int i0 = it * 64;
    const int iw = i0 + w * 16;
    const int lg = l >> 4, ll = l & 15;

    // K fragments (A operand): row i = iw + ll, d = 8lg + e + 32c
    f16x8 kf[4];
    {
        const u16* kp = qkv + (size_t)(b * TT + iw + ll) * QKVN + KOFF + hk * 128 + lg * 8;
#pragma unroll
        for (int c = 0; c < 4; ++c) kf[c] = *(const f16x8*)(kp + 32 * c);
    }

    f32x4 o[8] = {};
    float mrun[4] = {-1e30f, -1e30f, -1e30f, -1e30f};
    float lrun[4] = {0.f, 0.f, 0.f, 0.f};

    // staging lane geometry
    const int rq = 16 * w + (l >> 4);   // Q row (+4e)
    const int cq = l & 15;              // Q chunk slot
    const int dv = 32 * w + (l >> 3);   // Vt row (+8e)
    const int cv = l & 7;               // Vt chunk slot
    const u16* vbase = vtg + (size_t)((b * NKV + hk) * 128) * 1024;
    const u16* qbase = qkv + (size_t)(b * TT) * QKVN + h * 128;

    const int nt = it + 1;
    for (int jt = 0; jt < nt; ++jt) {
        const int j0 = jt * 64;
        __syncthreads();   // previous tile's reads done
        // stage Q tile (64 j-rows x 128 d), linear dest + pre-swizzled source
#pragma unroll
        for (int e = 0; e < 4; ++e) {
            int r = rq + 4 * e;
            int cg = cq ^ (r & 7);
            GLDS(qbase + (size_t)(j0 + r) * QKVN + cg * 8, Qs + (16 * w + 4 * e) * 128);
        }
        // stage V^T tile (128 d-rows x 64 j)
#pragma unroll
        for (int e = 0; e < 4; ++e) {
            int d = dv + 8 * e;
            int cg = cv ^ (d & 7);
            GLDS(vbase + (size_t)d * 1024 + j0 + cg * 8, Vt + (32 * w + 8 * e) * 64);
        }
        __syncthreads();   // drains vmcnt, staging visible

        // S = K . Q^T : 16 MFMAs (4 kc x 4 j-frags)
        f32x4 s[4] = {};
#pragma unroll
        for (int kc = 0; kc < 4; ++kc)
#pragma unroll
            for (int n = 0; n < 4; ++n) {
                f16x8 qf = *(const f16x8*)&Qs[(16 * n + ll) * 128 + (((lg + 4 * kc) ^ (ll & 7)) * 8)];
                s[n] = __builtin_amdgcn_mfma_f32_16x16x32_f16(kf[kc], qf, s[n], 0, 0, 0);
            }

        // causal mask: only the diagonal tile needs it (wave-uniform branch)
        if (jt == it) {
#pragma unroll
            for (int n = 0; n < 4; ++n)
#pragma unroll
                for (int r = 0; r < 4; ++r)
                    s[n][r] = (16 * n + ll <= 16 * w + 4 * lg + r) ? s[n][r] : -1e30f;
        }

        // online softmax over j (16 lanes x 4 frags), defer-max rescale
        float tmx[4];
        bool need = false;
#pragma unroll
        for (int r = 0; r < 4; ++r) {
            float tm = fmaxf(fmaxf(s[0][r], s[1][r]), fmaxf(s[2][r], s[3][r]));
            tm = fmaxf(tm, __shfl_xor(tm, 1, 16));
            tm = fmaxf(tm, __shfl_xor(tm, 2, 16));
            tm = fmaxf(tm, __shfl_xor(tm, 4, 16));
            tm = fmaxf(tm, __shfl_xor(tm, 8, 16));
            tmx[r] = tm;
            need |= (tm > mrun[r] + 8.0f);
        }
        if (__any(need)) {
#pragma unroll
            for (int r = 0; r < 4; ++r) {
                float mnew = fmaxf(mrun[r], tmx[r]);
                float al = __expf(mrun[r] - mnew);
                lrun[r] *= al;
                mrun[r] = mnew;
#pragma unroll
                for (int n = 0; n < 8; ++n) o[n][r] *= al;
            }
        }
        float p[4][4];
#pragma unroll
        for (int r = 0; r < 4; ++r) {
#pragma unroll
            for (int n = 0; n < 4; ++n) p[n][r] = __expf(s[n][r] - mrun[r]);
            float ps = p[0][r] + p[1][r] + p[2][r] + p[3][r];
            ps += __shfl_xor(ps, 1, 16);
            ps += __shfl_xor(ps, 2, 16);
            ps += __shfl_xor(ps, 4, 16);
            ps += __shfl_xor(ps, 8, 16);
            lrun[r] += ps;
        }

        // P: D-layout -> per-wave LDS -> A-layout fragments
        u16* pw = Ps + w * (16 * 72);
#pragma unroll
        for (int n = 0; n < 4; ++n)
#pragma unroll
            for (int r = 0; r < 4; ++r)
                pw[(4 * lg + r) * 72 + ll + 16 * n] = f2h(p[n][r]);
        f16x8 pa[2];
        pa[0] = *(const f16x8*)&pw[ll * 72 + 8 * lg];
        pa[1] = *(const f16x8*)&pw[ll * 72 + 8 * lg + 32];

        // O += P @ V : 16 MFMAs (8 d-frags x 2 kj)
#pragma unroll
        for (int n = 0; n < 8; ++n)
#pragma unroll
            for (int kj = 0; kj < 2; ++kj) {
                f16x8 vf = *(const f16x8*)&Vt[(16 * n + ll) * 64 + (((lg + 4 * kj) ^ (ll & 7)) * 8)];
                o[n] = __builtin_amdgcn_mfma_f32_16x16x32_f16(pa[kj], vf, o[n], 0, 0, 0);
            }
    }

    // epilogue: row i = iw + 4lg + r, col = h*128 + 16n + ll
    u16* dst = attnb + (size_t)(b * TT + iw + 4 * lg) * CC + h * 128 + ll;
#pragma unroll
    for (int r = 0; r < 4; ++r) {
        float inv = 1.0f / lrun[r];
#pragma unroll
        for (int n = 0; n < 8; ++n)
            dst[(size_t)r * CC + 16 * n] = f2h(o[n][r] * inv);
    }
}

// ---------------------------------------------------------------------------
extern "C" void kernel_launch(void* const* d_in, const int* in_sizes, int n_in,
                              void* d_out, int out_size, void* d_ws, size_t ws_size,
                              hipStream_t stream) {
    const float* x      = (const float*)d_in[0];
    const float* angles = (const float*)d_in[1];
    const float* wq     = (const float*)d_in[2];
    const float* wk     = (const float*)d_in[3];
    const float* wv     = (const float*)d_in[4];
    const float* wo     = (const float*)d_in[5];
    float* out = (float*)d_out;

    char* ws = (char*)d_ws;
    // lifetimes: Wt1 (qkv weights) dead after qkv gemm; vtg reuses its tail.
    // qkvb+p0+p1 head reused for fp32 out-partials (dead after attn / rope+vT).
    u16*   Wt1   = (u16*)ws;                           // [0, 12.58M)
    u16*   vtg   = (u16*)(ws + 8388608);               // [8.39M, 10.49M) over Wt1 tail
    u16*   xb    = (u16*)(ws + 12582912);              // [12.58M, 20.97M) also attnb
    u16*   qkvb  = (u16*)(ws + 20971520);              // [20.97M, 33.55M)
    u16*   p01   = (u16*)(ws + 33554432);              // [33.55M, 58.72M) 2 partials
    float* outp  = (float*)(ws + 20971520);            // [20.97M, 54.53M) 2 fp32 partials
    u16*   attnb = xb;

    // 1. x -> fp16
    conv_x<<<(MROWS * CC / 4 + 255) / 256, 256, 0, stream>>>(x, xb, MROWS * CC / 4);
    // 2. weights -> Wt1 = [Wq;Wk;Wv]^T (3072 x 2048) fp16
    conv_wT<<<dim3(64, 64), 256, 0, stream>>>(wq, Wt1, CC,  0);
    conv_wT<<<dim3(64, 16), 256, 0, stream>>>(wk, Wt1, 512, 2048);
    conv_wT<<<dim3(64, 16), 256, 0, stream>>>(wv, Wt1, 512, 2560);
    // 3. fused QKV projection, split-K=2 -> p01 (fp16 partials)
    gemm_f16<1><<<dim3(QKVN / 128, MROWS / 128, 2), 256, 0, stream>>>(
        xb, Wt1, (float*)nullptr, p01, MROWS, QKVN, CC, 1024);
    // 4. reduce + RoPE (q,k) -> qkvb ; reduce + transpose (v) -> vtg
    {
        int nq = MROWS * NH * 64, nk = MROWS * NKV * 64;
        rope_red<<<(nq + nk + 255) / 256, 256, 0, stream>>>(p01, qkvb, angles, nq, nq + nk);
        vT_red<<<dim3(32, 4, 8), 256, 0, stream>>>(p01, vtg);
    }
    // 5. attention -> attnb (fp16)
    attn_mfma<<<dim3(TT / 64, BB * NH), 256, 0, stream>>>(qkvb, vtg, attnb);
    // 6. Wo^T -> Wt1 head, out projection split-K=2 -> fp32 partials, reduce
    conv_wT<<<dim3(64, 64), 256, 0, stream>>>(wo, Wt1, CC, 0);
    gemm_f16<0><<<dim3(CC / 128, MROWS / 128, 2), 256, 0, stream>>>(
        attnb, Wt1, outp, (u16*)nullptr, MROWS, CC, CC, 1024);
    red_f32<<<(MROWS * CC / 4 + 255) / 256, 256, 0, stream>>>(outp, out, MROWS * CC / 4);
}

// Round 5
// 155.779 us; speedup vs baseline: 6.9787x; 1.0765x over previous
//
#include <hip/hip_runtime.h>
#include <hip/hip_bf16.h>
#include <math.h>

#define BB 2
#define TT 1024
#define CC 2048
#define NH 16
#define NKV 4
#define HD 128
#define MROWS 2048
#define QKVN 3072              // 2048 q + 512 k + 512 v
#define KOFF 2048
#define VOFF 2560

typedef unsigned short u16;
typedef unsigned int   u32;
typedef _Float16 f16;
typedef _Float16 f16x8 __attribute__((ext_vector_type(8)));
typedef float    f32x4 __attribute__((ext_vector_type(4)));

__device__ __forceinline__ u16 f2h(float f) {
    union { f16 h; u16 u; } x; x.h = (f16)f; return x.u;
}
__device__ __forceinline__ float h2f(u16 u) {
    union { u16 u; f16 h; } x; x.u = u; return (float)x.h;
}

#define GLDS(gp, lp) __builtin_amdgcn_global_load_lds( \
    (const __attribute__((address_space(1))) u32*)(gp), \
    (__attribute__((address_space(3))) u32*)(lp), 16, 0, 0)

// ---------------------------------------------------------------------------
// x fp32 -> fp16
// ---------------------------------------------------------------------------
__global__ void conv_x(const float* __restrict__ src, u16* __restrict__ dst, int n4) {
    int i = blockIdx.x * 256 + threadIdx.x;
    if (i >= n4) return;
    float4 v = ((const float4*)src)[i];
    ushort4 o;
    o.x = f2h(v.x); o.y = f2h(v.y); o.z = f2h(v.z); o.w = f2h(v.w);
    ((ushort4*)dst)[i] = o;
}

// ---------------------------------------------------------------------------
// Transpose-convert: Wt[row_off + n][k] = src[k][n]  (K=2048 fixed), fp16 out
// ---------------------------------------------------------------------------
__global__ __launch_bounds__(256) void conv_wT(const float* __restrict__ src,
                                               u16* __restrict__ Wt,
                                               int Nsrc, int row_off) {
    __shared__ float tile[32][33];
    const int k0 = blockIdx.x * 32;
    const int n0 = blockIdx.y * 32;
    const int t = threadIdx.x;
    const int r = t >> 3, c4 = (t & 7) * 4;
    float4 v = *(const float4*)&src[(size_t)(k0 + r) * Nsrc + n0 + c4];
    tile[r][c4 + 0] = v.x; tile[r][c4 + 1] = v.y;
    tile[r][c4 + 2] = v.z; tile[r][c4 + 3] = v.w;
    __syncthreads();
    ushort4 o;
    o.x = f2h(tile[c4 + 0][r]); o.y = f2h(tile[c4 + 1][r]);
    o.z = f2h(tile[c4 + 2][r]); o.w = f2h(tile[c4 + 3][r]);
    *(ushort4*)&Wt[(size_t)(row_off + n0 + r) * 2048 + k0 + c4] = o;
}

// ---------------------------------------------------------------------------
// RoPE + split-K reduce: qkv[m][col] = rope(p0[m][col] + p1[m][col]) for q,k.
// ---------------------------------------------------------------------------
__global__ void rope_red(const u16* __restrict__ pp, u16* __restrict__ qkv,
                         const float* __restrict__ angles, int nq, int ntot) {
    const size_t PSZ = (size_t)MROWS * QKVN;
    int idx = blockIdx.x * 256 + threadIdx.x;
    if (idx >= ntot) return;
    int p, col, m;
    if (idx < nq) {
        p = idx & 63; int rest = idx >> 6;
        int h = rest & 15; m = rest >> 4;
        col = h * 128 + 2 * p;
    } else {
        int j = idx - nq; p = j & 63; int rest = j >> 6;
        int h = rest & 3; m = rest >> 2;
        col = KOFF + h * 128 + 2 * p;
    }
    size_t off = (size_t)m * QKVN + col;
    u32 a = *(const u32*)(pp + off);
    u32 b = *(const u32*)(pp + PSZ + off);
    float x0 = h2f((u16)(a & 0xFFFF)) + h2f((u16)(b & 0xFFFF));
    float x1 = h2f((u16)(a >> 16))    + h2f((u16)(b >> 16));
    int tpos = m & (TT - 1);
    float ang = angles[tpos * 64 + p];
    float s = sinf(ang), c = cosf(ang);
    float r0 = c * x0 - s * x1, r1 = s * x0 + c * x1;
    *(u32*)(qkv + off) = (u32)f2h(r0) | ((u32)f2h(r1) << 16);
}

// ---------------------------------------------------------------------------
// V^T + split-K reduce: vtg[(b*NKV+hk)*128 + d][j] = p0.v + p1.v  (fp16)
// ---------------------------------------------------------------------------
__global__ __launch_bounds__(256) void vT_red(const u16* __restrict__ pp,
                                              u16* __restrict__ vtg) {
    const size_t PSZ = (size_t)MROWS * QKVN;
    __shared__ u16 tl[32][34];
    const int j0 = blockIdx.x * 32;
    const int d0 = blockIdx.y * 32;
    const int bhk = blockIdx.z;
    const int b = bhk >> 2, hk = bhk & 3;
    const int t = threadIdx.x;
    {
        int j_in = t >> 3, c4 = (t & 7) * 4;
        size_t off = (size_t)(b * TT + j0 + j_in) * QKVN + VOFF + hk * 128 + d0 + c4;
        ushort4 a = *(const ushort4*)(pp + off);
        ushort4 b4 = *(const ushort4*)(pp + PSZ + off);
        tl[j_in][c4 + 0] = f2h(h2f(a.x) + h2f(b4.x));
        tl[j_in][c4 + 1] = f2h(h2f(a.y) + h2f(b4.y));
        tl[j_in][c4 + 2] = f2h(h2f(a.z) + h2f(b4.z));
        tl[j_in][c4 + 3] = f2h(h2f(a.w) + h2f(b4.w));
    }
    __syncthreads();
    {
        int d_in = t >> 3, j4 = (t & 7) * 4;
        ushort4 o;
        o.x = tl[j4 + 0][d_in]; o.y = tl[j4 + 1][d_in];
        o.z = tl[j4 + 2][d_in]; o.w = tl[j4 + 3][d_in];
        *(ushort4*)&vtg[(size_t)(bhk * 128 + d0 + d_in) * 1024 + j0 + j4] = o;
    }
}

// ---------------------------------------------------------------------------
// fp16 MFMA GEMM, split-K via blockIdx.z.  128x128 tile, BK=32, 4 waves.
// ---------------------------------------------------------------------------
template <int OUTB>
__global__ __launch_bounds__(256) void gemm_f16(const u16* __restrict__ A,
                                                const u16* __restrict__ Bt,
                                                float* __restrict__ Cf,
                                                u16* __restrict__ Cb,
                                                int M, int N, int K, int klen) {
    __shared__ __align__(16) u16 As[128 * 32];
    __shared__ __align__(16) u16 Bs[128 * 32];
    const int t = threadIdx.x;
    const int l = t & 63;
    const int w = t >> 6;
    const int row0 = blockIdx.y * 128;
    const int col0 = blockIdx.x * 128;
    const int koff = blockIdx.z * klen;
    const int wr = w >> 1, wc = w & 1;

    const int srow0  = 16 * (2 * w) + (l >> 2);
    const int schunk = (l & 3) ^ ((l >> 2) & 3);
    const u16* aP0 = A  + (size_t)(row0 + srow0)      * K + schunk * 8;
    const u16* aP1 = A  + (size_t)(row0 + srow0 + 16) * K + schunk * 8;
    const u16* bP0 = Bt + (size_t)(col0 + srow0)      * K + schunk * 8;
    const u16* bP1 = Bt + (size_t)(col0 + srow0 + 16) * K + schunk * 8;
    u16* asl0 = As + (2 * w + 0) * 512;
    u16* asl1 = As + (2 * w + 1) * 512;
    u16* bsl0 = Bs + (2 * w + 0) * 512;
    u16* bsl1 = Bs + (2 * w + 1) * 512;

    f32x4 acc[4][4] = {};

    const int ar = wr * 64 + (l & 15);
    const int br = wc * 64 + (l & 15);
    const int lg = l >> 4;

    for (int k0 = koff; k0 < koff + klen; k0 += 32) {
        __syncthreads();
        GLDS(aP0 + k0, asl0);
        GLDS(aP1 + k0, asl1);
        GLDS(bP0 + k0, bsl0);
        GLDS(bP1 + k0, bsl1);
        __syncthreads();
        f16x8 af[4], bfr[4];
#pragma unroll
        for (int m = 0; m < 4; ++m) {
            int row = ar + 16 * m;
            af[m]  = *(const f16x8*)&As[row * 32 + ((lg ^ (row & 3)) * 8)];
            int col = br + 16 * m;
            bfr[m] = *(const f16x8*)&Bs[col * 32 + ((lg ^ (col & 3)) * 8)];
        }
#pragma unroll
        for (int m = 0; m < 4; ++m)
#pragma unroll
            for (int n = 0; n < 4; ++n)
                acc[m][n] = __builtin_amdgcn_mfma_f32_16x16x32_f16(
                    af[m], bfr[n], acc[m][n], 0, 0, 0);
    }

    const size_t zoff = (size_t)blockIdx.z * M * N;
    const int orow = row0 + wr * 64 + lg * 4;
    const int ocol = col0 + wc * 64 + (l & 15);
#pragma unroll
    for (int m = 0; m < 4; ++m)
#pragma unroll
        for (int n = 0; n < 4; ++n)
#pragma unroll
            for (int r = 0; r < 4; ++r) {
                size_t off = zoff + (size_t)(orow + 16 * m + r) * N + ocol + 16 * n;
                if (OUTB) Cb[off] = f2h(acc[m][n][r]);
                else      Cf[off] = acc[m][n][r];
            }
}

// ---------------------------------------------------------------------------
// out = p0 + p1 (fp32 elementwise)
// ---------------------------------------------------------------------------
__global__ void red_f32(const float* __restrict__ pp, float* __restrict__ out, int n4) {
    int i = blockIdx.x * 256 + threadIdx.x;
    if (i >= n4) return;
    const size_t PSZ = (size_t)MROWS * CC;
    float4 a = ((const float4*)pp)[i];
    float4 b = ((const float4*)(pp + PSZ))[i];
    ((float4*)out)[i] = make_float4(a.x + b.x, a.y + b.y, a.z + b.z, a.w + b.w);
}

// ---------------------------------------------------------------------------
// MFMA flash attention (swapped roles), v3:
//  - triangle pairing: block p handles i-tiles {p, 15-p} -> 17 j-tiles/block,
//    perfectly balanced.  grid (8, B*NH) = 256 blocks.
//  - double-buffered Q/Vt staging: loads for tile t+1 issued before compute
//    on tile t; one vmcnt(0)+barrier per tile (__syncthreads).
//  - defer-max rescale (thr=8): shfl max-reduce only when triggered; lrun as
//    per-lane partial, reduced once in epilogue.
// ---------------------------------------------------------------------------
__global__ __launch_bounds__(256) void attn_mfma(const u16* __restrict__ qkv,
                                                 const u16* __restrict__ vtg,
                                                 u16* __restrict__ attnb) {
    __shared__ __align__(16) u16 Qs0[64 * 128];   // [j_loc][d], chunk-swizzled
    __shared__ __align__(16) u16 Qs1[64 * 128];
    __shared__ __align__(16) u16 Vt0[128 * 64];   // [d][j_loc], chunk-swizzled
    __shared__ __align__(16) u16 Vt1[128 * 64];
    __shared__ __align__(16) u16 Ps[4 * 16 * 72];

    const int t = threadIdx.x, l = t & 63, w = t >> 6;
    const int bh = blockIdx.y;
    const int b = bh >> 4, h = bh & 15, hk = h & 3;
    const int lg = l >> 4, ll = l & 15;

    const u16* qbase = qkv + (size_t)(b * TT) * QKVN + h * 128;
    const u16* vbase = vtg + (size_t)((b * NKV + hk) * 128) * 1024;

    // staging lane geometry
    const int rq = 16 * w + (l >> 4);   // Q row (+4e)
    const int cq = l & 15;              // Q chunk slot
    const int dv = 32 * w + (l >> 3);   // Vt row (+8e)
    const int cv = l & 7;               // Vt chunk slot

#define STAGE(j0v, Qd, Vd) do {                                               \
    _Pragma("unroll")                                                         \
    for (int e_ = 0; e_ < 4; ++e_) {                                          \
        int r_ = rq + 4 * e_;                                                 \
        GLDS(qbase + (size_t)((j0v) + r_) * QKVN + ((cq ^ (r_ & 7)) * 8),     \
             (Qd) + (16 * w + 4 * e_) * 128);                                 \
    }                                                                         \
    _Pragma("unroll")                                                         \
    for (int e_ = 0; e_ < 4; ++e_) {                                          \
        int d_ = dv + 8 * e_;                                                 \
        GLDS(vbase + (size_t)d_ * 1024 + (j0v) + ((cv ^ (d_ & 7)) * 8),       \
             (Vd) + (32 * w + 8 * e_) * 64);                                  \
    }                                                                         \
} while (0)

#pragma unroll 1
    for (int ph = 0; ph < 2; ++ph) {
        const int it = ph ? (15 - blockIdx.x) : blockIdx.x;
        const int iw = it * 64 + w * 16;

        // K fragments (A operand): row i = iw + ll, d = 8lg + e + 32c
        f16x8 kf[4];
        {
            const u16* kp = qkv + (size_t)(b * TT + iw + ll) * QKVN + KOFF + hk * 128 + lg * 8;
#pragma unroll
            for (int c = 0; c < 4; ++c) kf[c] = *(const f16x8*)(kp + 32 * c);
        }

        f32x4 o[8] = {};
        float mrun[4] = {-1e30f, -1e30f, -1e30f, -1e30f};
        float lrun[4] = {0.f, 0.f, 0.f, 0.f};

        const int nt = it + 1;
        STAGE(0, Qs0, Vt0);
        __syncthreads();

#pragma unroll 1
        for (int jt = 0; jt < nt; ++jt) {
            u16* Qc = (jt & 1) ? Qs1 : Qs0;
            u16* Vc = (jt & 1) ? Vt1 : Vt0;
            if (jt + 1 < nt) {
                u16* Qn = (jt & 1) ? Qs0 : Qs1;
                u16* Vn = (jt & 1) ? Vt0 : Vt1;
                STAGE((jt + 1) * 64, Qn, Vn);
            }

            // S = K . Q^T : 16 MFMAs (4 kc x 4 j-frags)
            f32x4 s[4] = {};
#pragma unroll
            for (int kc = 0; kc < 4; ++kc)
#pragma unroll
                for (int n = 0; n < 4; ++n) {
                    f16x8 qf = *(const f16x8*)&Qc[(16 * n + ll) * 128 + (((lg + 4 * kc) ^ (ll & 7)) * 8)];
                    s[n] = __builtin_amdgcn_mfma_f32_16x16x32_f16(kf[kc], qf, s[n], 0, 0, 0);
                }

            // causal mask: only the diagonal tile (wave-uniform branch)
            if (jt == it) {
#pragma unroll
                for (int n = 0; n < 4; ++n)
#pragma unroll
                    for (int r = 0; r < 4; ++r)
                        s[n][r] = (16 * n + ll <= 16 * w + 4 * lg + r) ? s[n][r] : -1e30f;
            }

            // defer-max online softmax: cheap per-lane trigger check
            float tml[4];
            bool need = false;
#pragma unroll
            for (int r = 0; r < 4; ++r) {
                float tm = fmaxf(fmaxf(s[0][r], s[1][r]), fmaxf(s[2][r], s[3][r]));
                tml[r] = tm;
                need |= (tm > mrun[r] + 8.0f);
            }
            if (__any(need)) {
#pragma unroll
                for (int r = 0; r < 4; ++r) {
                    float tm = tml[r];
                    tm = fmaxf(tm, __shfl_xor(tm, 1, 16));
                    tm = fmaxf(tm, __shfl_xor(tm, 2, 16));
                    tm = fmaxf(tm, __shfl_xor(tm, 4, 16));
                    tm = fmaxf(tm, __shfl_xor(tm, 8, 16));
                    float mnew = fmaxf(mrun[r], tm);
                    float al = __expf(mrun[r] - mnew);
                    lrun[r] *= al;
                    mrun[r] = mnew;
#pragma unroll
                    for (int n = 0; n < 8; ++n) o[n][r] *= al;
                }
            }
            float p[4][4];
#pragma unroll
            for (int r = 0; r < 4; ++r) {
                float ps = 0.f;
#pragma unroll
                for (int n = 0; n < 4; ++n) { p[n][r] = __expf(s[n][r] - mrun[r]); ps += p[n][r]; }
                lrun[r] += ps;   // per-lane partial; reduced in epilogue
            }

            // P: D-layout -> per-wave LDS -> A-layout fragments
            u16* pw = Ps + w * (16 * 72);
#pragma unroll
            for (int n = 0; n < 4; ++n)
#pragma unroll
                for (int r = 0; r < 4; ++r)
                    pw[(4 * lg + r) * 72 + ll + 16 * n] = f2h(p[n][r]);
            f16x8 pa0 = *(const f16x8*)&pw[ll * 72 + 8 * lg];
            f16x8 pa1 = *(const f16x8*)&pw[ll * 72 + 8 * lg + 32];

            // O += P @ V : 16 MFMAs (8 d-frags x 2 kj)
#pragma unroll
            for (int n = 0; n < 8; ++n) {
                f16x8 vf0 = *(const f16x8*)&Vc[(16 * n + ll) * 64 + ((lg ^ (ll & 7)) * 8)];
                o[n] = __builtin_amdgcn_mfma_f32_16x16x32_f16(pa0, vf0, o[n], 0, 0, 0);
                f16x8 vf1 = *(const f16x8*)&Vc[(16 * n + ll) * 64 + (((lg + 4) ^ (ll & 7)) * 8)];
                o[n] = __builtin_amdgcn_mfma_f32_16x16x32_f16(pa1, vf1, o[n], 0, 0, 0);
            }

            __syncthreads();   // drains vmcnt (next tile staged) + LDS reuse
        }

        // epilogue: row i = iw + 4lg + r, col = h*128 + 16n + ll
        u16* dst = attnb + (size_t)(b * TT + iw + 4 * lg) * CC + h * 128 + ll;
#pragma unroll
        for (int r = 0; r < 4; ++r) {
            float L = lrun[r];
            L += __shfl_xor(L, 1, 16);
            L += __shfl_xor(L, 2, 16);
            L += __shfl_xor(L, 4, 16);
            L += __shfl_xor(L, 8, 16);
            float inv = 1.0f / L;
#pragma unroll
            for (int n = 0; n < 8; ++n)
                dst[(size_t)r * CC + 16 * n] = f2h(o[n][r] * inv);
        }
    }
#undef STAGE
}

// ---------------------------------------------------------------------------
extern "C" void kernel_launch(void* const* d_in, const int* in_sizes, int n_in,
                              void* d_out, int out_size, void* d_ws, size_t ws_size,
                              hipStream_t stream) {
    const float* x      = (const float*)d_in[0];
    const float* angles = (const float*)d_in[1];
    const float* wq     = (const float*)d_in[2];
    const float* wk     = (const float*)d_in[3];
    const float* wv     = (const float*)d_in[4];
    const float* wo     = (const float*)d_in[5];
    float* out = (float*)d_out;

    char* ws = (char*)d_ws;
    u16*   Wt1   = (u16*)ws;                           // [0, 12.58M)
    u16*   vtg   = (u16*)(ws + 8388608);               // [8.39M, 10.49M) over Wt1 tail
    u16*   xb    = (u16*)(ws + 12582912);              // [12.58M, 20.97M) also attnb
    u16*   qkvb  = (u16*)(ws + 20971520);              // [20.97M, 33.55M)
    u16*   p01   = (u16*)(ws + 33554432);              // [33.55M, 58.72M) 2 partials
    float* outp  = (float*)(ws + 20971520);            // [20.97M, 54.53M) 2 fp32 partials
    u16*   attnb = xb;

    // 1. x -> fp16
    conv_x<<<(MROWS * CC / 4 + 255) / 256, 256, 0, stream>>>(x, xb, MROWS * CC / 4);
    // 2. weights -> Wt1 = [Wq;Wk;Wv]^T (3072 x 2048) fp16
    conv_wT<<<dim3(64, 64), 256, 0, stream>>>(wq, Wt1, CC,  0);
    conv_wT<<<dim3(64, 16), 256, 0, stream>>>(wk, Wt1, 512, 2048);
    conv_wT<<<dim3(64, 16), 256, 0, stream>>>(wv, Wt1, 512, 2560);
    // 3. fused QKV projection, split-K=2 -> p01 (fp16 partials)
    gemm_f16<1><<<dim3(QKVN / 128, MROWS / 128, 2), 256, 0, stream>>>(
        xb, Wt1, (float*)nullptr, p01, MROWS, QKVN, CC, 1024);
    // 4. reduce + RoPE (q,k) -> qkvb ; reduce + transpose (v) -> vtg
    {
        int nq = MROWS * NH * 64, nk = MROWS * NKV * 64;
        rope_red<<<(nq + nk + 255) / 256, 256, 0, stream>>>(p01, qkvb, angles, nq, nq + nk);
        vT_red<<<dim3(32, 4, 8), 256, 0, stream>>>(p01, vtg);
    }
    // 5. attention (paired-balanced, double-buffered) -> attnb (fp16)
    attn_mfma<<<dim3(8, BB * NH), 256, 0, stream>>>(qkvb, vtg, attnb);
    // 6. Wo^T -> Wt1 head, out projection split-K=2 -> fp32 partials, reduce
    conv_wT<<<dim3(64, 64), 256, 0, stream>>>(wo, Wt1, CC, 0);
    gemm_f16<0><<<dim3(CC / 128, MROWS / 128, 2), 256, 0, stream>>>(
        attnb, Wt1, outp, (u16*)nullptr, MROWS, CC, CC, 1024);
    red_f32<<<(MROWS * CC / 4 + 255) / 256, 256, 0, stream>>>(outp, out, MROWS * CC / 4);
}

// Round 6
// 143.076 us; speedup vs baseline: 7.5983x; 1.0888x over previous
//
#include <hip/hip_runtime.h>
#include <hip/hip_bf16.h>
#include <math.h>

#define BB 2
#define TT 1024
#define CC 2048
#define NH 16
#define NKV 4
#define HD 128
#define MROWS 2048
#define QKVN 3072              // 2048 q + 512 k + 512 v
#define KOFF 2048
#define VOFF 2560

typedef unsigned short u16;
typedef unsigned int   u32;
typedef _Float16 f16;
typedef _Float16 f16x8 __attribute__((ext_vector_type(8)));
typedef short    s16x8 __attribute__((ext_vector_type(8)));
typedef float    f32x4 __attribute__((ext_vector_type(4)));

__device__ __forceinline__ u16 f2h(float f) {
    union { f16 h; u16 u; } x; x.h = (f16)f; return x.u;
}
__device__ __forceinline__ float h2f(u16 u) {
    union { u16 u; f16 h; } x; x.u = u; return (float)x.h;
}

#define GLDS(gp, lp) __builtin_amdgcn_global_load_lds( \
    (const __attribute__((address_space(1))) u32*)(gp), \
    (__attribute__((address_space(3))) u32*)(lp), 16, 0, 0)

// ---------------------------------------------------------------------------
// x fp32 -> fp16
// ---------------------------------------------------------------------------
__global__ void conv_x(const float* __restrict__ src, u16* __restrict__ dst, int n4) {
    int i = blockIdx.x * 256 + threadIdx.x;
    if (i >= n4) return;
    float4 v = ((const float4*)src)[i];
    ushort4 o;
    o.x = f2h(v.x); o.y = f2h(v.y); o.z = f2h(v.z); o.w = f2h(v.w);
    ((ushort4*)dst)[i] = o;
}

// ---------------------------------------------------------------------------
// Transpose-convert: Wt[row_off + n][k] = src[k][n]  (K=2048 fixed), fp16 out
// ---------------------------------------------------------------------------
__global__ __launch_bounds__(256) void conv_wT(const float* __restrict__ src,
                                               u16* __restrict__ Wt,
                                               int Nsrc, int row_off) {
    __shared__ float tile[32][33];
    const int k0 = blockIdx.x * 32;
    const int n0 = blockIdx.y * 32;
    const int t = threadIdx.x;
    const int r = t >> 3, c4 = (t & 7) * 4;
    float4 v = *(const float4*)&src[(size_t)(k0 + r) * Nsrc + n0 + c4];
    tile[r][c4 + 0] = v.x; tile[r][c4 + 1] = v.y;
    tile[r][c4 + 2] = v.z; tile[r][c4 + 3] = v.w;
    __syncthreads();
    ushort4 o;
    o.x = f2h(tile[c4 + 0][r]); o.y = f2h(tile[c4 + 1][r]);
    o.z = f2h(tile[c4 + 2][r]); o.w = f2h(tile[c4 + 3][r]);
    *(ushort4*)&Wt[(size_t)(row_off + n0 + r) * 2048 + k0 + c4] = o;
}

// ---------------------------------------------------------------------------
// RoPE + split-K reduce, vectorized: 4 pairs (16 B) per thread.
// ---------------------------------------------------------------------------
__global__ void rope_red(const u16* __restrict__ pp, u16* __restrict__ qkv,
                         const float* __restrict__ angles, int nq4, int ntot4) {
    const size_t PSZ = (size_t)MROWS * QKVN;
    int idx = blockIdx.x * 256 + threadIdx.x;
    if (idx >= ntot4) return;
    int p4, col, m;
    if (idx < nq4) {
        p4 = idx & 15; int rest = idx >> 4;
        int h = rest & 15; m = rest >> 4;
        col = h * 128 + p4 * 8;
    } else {
        int j = idx - nq4; p4 = j & 15; int rest = j >> 4;
        int h = rest & 3; m = rest >> 2;
        col = KOFF + h * 128 + p4 * 8;
    }
    size_t off = (size_t)m * QKVN + col;
    s16x8 a = *(const s16x8*)(pp + off);
    s16x8 b = *(const s16x8*)(pp + PSZ + off);
    int tpos = m & (TT - 1);
    float4 ang = *(const float4*)&angles[tpos * 64 + p4 * 4];
    float an[4] = {ang.x, ang.y, ang.z, ang.w};
    s16x8 o;
#pragma unroll
    for (int u = 0; u < 4; ++u) {
        float x0 = h2f((u16)a[2 * u])     + h2f((u16)b[2 * u]);
        float x1 = h2f((u16)a[2 * u + 1]) + h2f((u16)b[2 * u + 1]);
        float s = sinf(an[u]), c = cosf(an[u]);
        o[2 * u]     = (short)f2h(c * x0 - s * x1);
        o[2 * u + 1] = (short)f2h(s * x0 + c * x1);
    }
    *(s16x8*)(qkv + off) = o;
}

// ---------------------------------------------------------------------------
// V^T + split-K reduce: vtg[(b*NKV+hk)*128 + d][j] = p0.v + p1.v  (fp16)
// ---------------------------------------------------------------------------
__global__ __launch_bounds__(256) void vT_red(const u16* __restrict__ pp,
                                              u16* __restrict__ vtg) {
    const size_t PSZ = (size_t)MROWS * QKVN;
    __shared__ u16 tl[32][34];
    const int j0 = blockIdx.x * 32;
    const int d0 = blockIdx.y * 32;
    const int bhk = blockIdx.z;
    const int b = bhk >> 2, hk = bhk & 3;
    const int t = threadIdx.x;
    {
        int j_in = t >> 3, c4 = (t & 7) * 4;
        size_t off = (size_t)(b * TT + j0 + j_in) * QKVN + VOFF + hk * 128 + d0 + c4;
        ushort4 a = *(const ushort4*)(pp + off);
        ushort4 b4 = *(const ushort4*)(pp + PSZ + off);
        tl[j_in][c4 + 0] = f2h(h2f(a.x) + h2f(b4.x));
        tl[j_in][c4 + 1] = f2h(h2f(a.y) + h2f(b4.y));
        tl[j_in][c4 + 2] = f2h(h2f(a.z) + h2f(b4.z));
        tl[j_in][c4 + 3] = f2h(h2f(a.w) + h2f(b4.w));
    }
    __syncthreads();
    {
        int d_in = t >> 3, j4 = (t & 7) * 4;
        ushort4 o;
        o.x = tl[j4 + 0][d_in]; o.y = tl[j4 + 1][d_in];
        o.z = tl[j4 + 2][d_in]; o.w = tl[j4 + 3][d_in];
        *(ushort4*)&vtg[(size_t)(bhk * 128 + d0 + d_in) * 1024 + j0 + j4] = o;
    }
}

// ---------------------------------------------------------------------------
// fp16 MFMA GEMM v2: 128x128 tile, BK=64, 4 waves (2x2 of 64x64),
// double-buffered LDS (64 KB), one barrier per K-step, (row&7) XOR swizzle
// -> conflict-free ds_read_b128.  Split-K via blockIdx.z (klen multiple of 128).
// ---------------------------------------------------------------------------
template <int OUTB>
__global__ __launch_bounds__(256) void gemm_f16(const u16* __restrict__ A,
                                                const u16* __restrict__ Bt,
                                                float* __restrict__ Cf,
                                                u16* __restrict__ Cb,
                                                int M, int N, int K, int klen) {
    __shared__ __align__(16) u16 As0[128 * 64];
    __shared__ __align__(16) u16 As1[128 * 64];
    __shared__ __align__(16) u16 Bs0[128 * 64];
    __shared__ __align__(16) u16 Bs1[128 * 64];
    const int t = threadIdx.x;
    const int l = t & 63;
    const int w = t >> 6;
    const int row0 = blockIdx.y * 128;
    const int col0 = blockIdx.x * 128;
    const int koff = blockIdx.z * klen;
    const int wr = w >> 1, wc = w & 1;
    const int lg = l >> 4, ll = l & 15;

    f32x4 acc[4][4] = {};

// stage one 128x64 A-tile + B-tile into (AS,BS): wave w covers rows 32w..32w+31
// via 4 insts of 8 rows; LDS linear dest, source chunk pre-swizzled by row&7.
#define GSTAGE(AS, BS, k0v) do {                                              \
    _Pragma("unroll")                                                         \
    for (int e_ = 0; e_ < 4; ++e_) {                                          \
        int r_ = 32 * w + 8 * e_ + (l >> 3);                                  \
        int cg_ = (l & 7) ^ (r_ & 7);                                         \
        GLDS(A  + (size_t)(row0 + r_) * K + (k0v) + cg_ * 8,                  \
             (AS) + (32 * w + 8 * e_) * 64);                                  \
        GLDS(Bt + (size_t)(col0 + r_) * K + (k0v) + cg_ * 8,                  \
             (BS) + (32 * w + 8 * e_) * 64);                                  \
    }                                                                         \
} while (0)

#define GCOMP(AS, BS) do {                                                    \
    _Pragma("unroll")                                                         \
    for (int kc_ = 0; kc_ < 2; ++kc_) {                                       \
        f16x8 af_[4], bf_[4];                                                 \
        _Pragma("unroll")                                                     \
        for (int m_ = 0; m_ < 4; ++m_) {                                      \
            int row_ = wr * 64 + 16 * m_ + ll;                                \
            af_[m_] = *(const f16x8*)&(AS)[row_ * 64 +                        \
                        (((lg + 4 * kc_) ^ (ll & 7)) * 8)];                   \
            int col_ = wc * 64 + 16 * m_ + ll;                                \
            bf_[m_] = *(const f16x8*)&(BS)[col_ * 64 +                        \
                        (((lg + 4 * kc_) ^ (ll & 7)) * 8)];                   \
        }                                                                     \
        _Pragma("unroll")                                                     \
        for (int m_ = 0; m_ < 4; ++m_)                                        \
            _Pragma("unroll")                                                 \
            for (int n_ = 0; n_ < 4; ++n_)                                    \
                acc[m_][n_] = __builtin_amdgcn_mfma_f32_16x16x32_f16(         \
                    af_[m_], bf_[n_], acc[m_][n_], 0, 0, 0);                  \
    }                                                                         \
} while (0)

    const int n = klen >> 6;   // K-steps of 64; klen multiple of 128 -> n even
    GSTAGE(As0, Bs0, koff);
    __syncthreads();
#pragma unroll 1
    for (int i = 0; i < n; i += 2) {
        GSTAGE(As1, Bs1, koff + (i + 1) * 64);
        GCOMP(As0, Bs0);
        __syncthreads();
        if (i + 2 < n) GSTAGE(As0, Bs0, koff + (i + 2) * 64);
        GCOMP(As1, Bs1);
        __syncthreads();
    }
#undef GSTAGE
#undef GCOMP

    const size_t zoff = (size_t)blockIdx.z * M * N;
    const int orow = row0 + wr * 64 + lg * 4;
    const int ocol = col0 + wc * 64 + ll;
#pragma unroll
    for (int m = 0; m < 4; ++m)
#pragma unroll
        for (int nn = 0; nn < 4; ++nn)
#pragma unroll
            for (int r = 0; r < 4; ++r) {
                size_t off = zoff + (size_t)(orow + 16 * m + r) * N + ocol + 16 * nn;
                if (OUTB) Cb[off] = f2h(acc[m][nn][r]);
                else      Cf[off] = acc[m][nn][r];
            }
}

// ---------------------------------------------------------------------------
// out = p0 + p1 (fp32 elementwise)
// ---------------------------------------------------------------------------
__global__ void red_f32(const float* __restrict__ pp, float* __restrict__ out, int n4) {
    int i = blockIdx.x * 256 + threadIdx.x;
    if (i >= n4) return;
    const size_t PSZ = (size_t)MROWS * CC;
    float4 a = ((const float4*)pp)[i];
    float4 b = ((const float4*)(pp + PSZ))[i];
    ((float4*)out)[i] = make_float4(a.x + b.x, a.y + b.y, a.z + b.z, a.w + b.w);
}

// ---------------------------------------------------------------------------
// MFMA flash attention (swapped roles): triangle-paired blocks, double-buffered
// Q/Vt staging, defer-max rescale.  (unchanged from round 5)
// ---------------------------------------------------------------------------
__global__ __launch_bounds__(256) void attn_mfma(const u16* __restrict__ qkv,
                                                 const u16* __restrict__ vtg,
                                                 u16* __restrict__ attnb) {
    __shared__ __align__(16) u16 Qs0[64 * 128];
    __shared__ __align__(16) u16 Qs1[64 * 128];
    __shared__ __align__(16) u16 Vt0[128 * 64];
    __shared__ __align__(16) u16 Vt1[128 * 64];
    __shared__ __align__(16) u16 Ps[4 * 16 * 72];

    const int t = threadIdx.x, l = t & 63, w = t >> 6;
    const int bh = blockIdx.y;
    const int b = bh >> 4, h = bh & 15, hk = h & 3;
    const int lg = l >> 4, ll = l & 15;

    const u16* qbase = qkv + (size_t)(b * TT) * QKVN + h * 128;
    const u16* vbase = vtg + (size_t)((b * NKV + hk) * 128) * 1024;

    const int rq = 16 * w + (l >> 4);
    const int cq = l & 15;
    const int dv = 32 * w + (l >> 3);
    const int cv = l & 7;

#define STAGE(j0v, Qd, Vd) do {                                               \
    _Pragma("unroll")                                                         \
    for (int e_ = 0; e_ < 4; ++e_) {                                          \
        int r_ = rq + 4 * e_;                                                 \
        GLDS(qbase + (size_t)((j0v) + r_) * QKVN + ((cq ^ (r_ & 7)) * 8),     \
             (Qd) + (16 * w + 4 * e_) * 128);                                 \
    }                                                                         \
    _Pragma("unroll")                                                         \
    for (int e_ = 0; e_ < 4; ++e_) {                                          \
        int d_ = dv + 8 * e_;                                                 \
        GLDS(vbase + (size_t)d_ * 1024 + (j0v) + ((cv ^ (d_ & 7)) * 8),       \
             (Vd) + (32 * w + 8 * e_) * 64);                                  \
    }                                                                         \
} while (0)

#pragma unroll 1
    for (int ph = 0; ph < 2; ++ph) {
        const int it = ph ? (15 - blockIdx.x) : blockIdx.x;
        const int iw = it * 64 + w * 16;

        f16x8 kf[4];
        {
            const u16* kp = qkv + (size_t)(b * TT + iw + ll) * QKVN + KOFF + hk * 128 + lg * 8;
#pragma unroll
            for (int c = 0; c < 4; ++c) kf[c] = *(const f16x8*)(kp + 32 * c);
        }

        f32x4 o[8] = {};
        float mrun[4] = {-1e30f, -1e30f, -1e30f, -1e30f};
        float lrun[4] = {0.f, 0.f, 0.f, 0.f};

        const int nt = it + 1;
        STAGE(0, Qs0, Vt0);
        __syncthreads();

#pragma unroll 1
        for (int jt = 0; jt < nt; ++jt) {
            u16* Qc = (jt & 1) ? Qs1 : Qs0;
            u16* Vc = (jt & 1) ? Vt1 : Vt0;
            if (jt + 1 < nt) {
                u16* Qn = (jt & 1) ? Qs0 : Qs1;
                u16* Vn = (jt & 1) ? Vt0 : Vt1;
                STAGE((jt + 1) * 64, Qn, Vn);
            }

            f32x4 s[4] = {};
#pragma unroll
            for (int kc = 0; kc < 4; ++kc)
#pragma unroll
                for (int n = 0; n < 4; ++n) {
                    f16x8 qf = *(const f16x8*)&Qc[(16 * n + ll) * 128 + (((lg + 4 * kc) ^ (ll & 7)) * 8)];
                    s[n] = __builtin_amdgcn_mfma_f32_16x16x32_f16(kf[kc], qf, s[n], 0, 0, 0);
                }

            if (jt == it) {
#pragma unroll
                for (int n = 0; n < 4; ++n)
#pragma unroll
                    for (int r = 0; r < 4; ++r)
                        s[n][r] = (16 * n + ll <= 16 * w + 4 * lg + r) ? s[n][r] : -1e30f;
            }

            float tml[4];
            bool need = false;
#pragma unroll
            for (int r = 0; r < 4; ++r) {
                float tm = fmaxf(fmaxf(s[0][r], s[1][r]), fmaxf(s[2][r], s[3][r]));
                tml[r] = tm;
                need |= (tm > mrun[r] + 8.0f);
            }
            if (__any(need)) {
#pragma unroll
                for (int r = 0; r < 4; ++r) {
                    float tm = tml[r];
                    tm = fmaxf(tm, __shfl_xor(tm, 1, 16));
                    tm = fmaxf(tm, __shfl_xor(tm, 2, 16));
                    tm = fmaxf(tm, __shfl_xor(tm, 4, 16));
                    tm = fmaxf(tm, __shfl_xor(tm, 8, 16));
                    float mnew = fmaxf(mrun[r], tm);
                    float al = __expf(mrun[r] - mnew);
                    lrun[r] *= al;
                    mrun[r] = mnew;
#pragma unroll
                    for (int n = 0; n < 8; ++n) o[n][r] *= al;
                }
            }
            float p[4][4];
#pragma unroll
            for (int r = 0; r < 4; ++r) {
                float ps = 0.f;
#pragma unroll
                for (int n = 0; n < 4; ++n) { p[n][r] = __expf(s[n][r] - mrun[r]); ps += p[n][r]; }
                lrun[r] += ps;
            }

            u16* pw = Ps + w * (16 * 72);
#pragma unroll
            for (int n = 0; n < 4; ++n)
#pragma unroll
                for (int r = 0; r < 4; ++r)
                    pw[(4 * lg + r) * 72 + ll + 16 * n] = f2h(p[n][r]);
            f16x8 pa0 = *(const f16x8*)&pw[ll * 72 + 8 * lg];
            f16x8 pa1 = *(const f16x8*)&pw[ll * 72 + 8 * lg + 32];

#pragma unroll
            for (int n = 0; n < 8; ++n) {
                f16x8 vf0 = *(const f16x8*)&Vc[(16 * n + ll) * 64 + ((lg ^ (ll & 7)) * 8)];
                o[n] = __builtin_amdgcn_mfma_f32_16x16x32_f16(pa0, vf0, o[n], 0, 0, 0);
                f16x8 vf1 = *(const f16x8*)&Vc[(16 * n + ll) * 64 + (((lg + 4) ^ (ll & 7)) * 8)];
                o[n] = __builtin_amdgcn_mfma_f32_16x16x32_f16(pa1, vf1, o[n], 0, 0, 0);
            }

            __syncthreads();
        }

        u16* dst = attnb + (size_t)(b * TT + iw + 4 * lg) * CC + h * 128 + ll;
#pragma unroll
        for (int r = 0; r < 4; ++r) {
            float L = lrun[r];
            L += __shfl_xor(L, 1, 16);
            L += __shfl_xor(L, 2, 16);
            L += __shfl_xor(L, 4, 16);
            L += __shfl_xor(L, 8, 16);
            float inv = 1.0f / L;
#pragma unroll
            for (int n = 0; n < 8; ++n)
                dst[(size_t)r * CC + 16 * n] = f2h(o[n][r] * inv);
        }
    }
#undef STAGE
}

// ---------------------------------------------------------------------------
extern "C" void kernel_launch(void* const* d_in, const int* in_sizes, int n_in,
                              void* d_out, int out_size, void* d_ws, size_t ws_size,
                              hipStream_t stream) {
    const float* x      = (const float*)d_in[0];
    const float* angles = (const float*)d_in[1];
    const float* wq     = (const float*)d_in[2];
    const float* wk     = (const float*)d_in[3];
    const float* wv     = (const float*)d_in[4];
    const float* wo     = (const float*)d_in[5];
    float* out = (float*)d_out;

    char* ws = (char*)d_ws;
    u16*   Wt1   = (u16*)ws;                           // [0, 12.58M)
    u16*   vtg   = (u16*)(ws + 8388608);               // [8.39M, 10.49M) over Wt1 tail
    u16*   xb    = (u16*)(ws + 12582912);              // [12.58M, 20.97M) also attnb
    u16*   qkvb  = (u16*)(ws + 20971520);              // [20.97M, 33.55M)
    u16*   p01   = (u16*)(ws + 33554432);              // [33.55M, 58.72M) 2 fp16 partials
    float* outp  = (float*)(ws + 20971520);            // [20.97M, 54.53M) 2 fp32 partials
    u16*   attnb = xb;

    // 1. x -> fp16
    conv_x<<<(MROWS * CC / 4 + 255) / 256, 256, 0, stream>>>(x, xb, MROWS * CC / 4);
    // 2. weights -> Wt1 = [Wq;Wk;Wv]^T (3072 x 2048) fp16
    conv_wT<<<dim3(64, 64), 256, 0, stream>>>(wq, Wt1, CC,  0);
    conv_wT<<<dim3(64, 16), 256, 0, stream>>>(wk, Wt1, 512, 2048);
    conv_wT<<<dim3(64, 16), 256, 0, stream>>>(wv, Wt1, 512, 2560);
    // 3. fused QKV projection, split-K=2 -> p01 (fp16 partials)
    gemm_f16<1><<<dim3(QKVN / 128, MROWS / 128, 2), 256, 0, stream>>>(
        xb, Wt1, (float*)nullptr, p01, MROWS, QKVN, CC, 1024);
    // 4. reduce + RoPE (q,k) -> qkvb ; reduce + transpose (v) -> vtg
    {
        int nq4 = MROWS * NH * 16, nk4 = MROWS * NKV * 16;
        rope_red<<<(nq4 + nk4 + 255) / 256, 256, 0, stream>>>(p01, qkvb, angles, nq4, nq4 + nk4);
        vT_red<<<dim3(32, 4, 8), 256, 0, stream>>>(p01, vtg);
    }
    // 5. attention (paired-balanced, double-buffered) -> attnb (fp16)
    attn_mfma<<<dim3(8, BB * NH), 256, 0, stream>>>(qkvb, vtg, attnb);
    // 6. Wo^T -> Wt1 head, out projection split-K=2 -> fp32 partials, reduce
    conv_wT<<<dim3(64, 64), 256, 0, stream>>>(wo, Wt1, CC, 0);
    gemm_f16<0><<<dim3(CC / 128, MROWS / 128, 2), 256, 0, stream>>>(
        attnb, Wt1, outp, (u16*)nullptr, MROWS, CC, CC, 1024);
    red_f32<<<(MROWS * CC / 4 + 255) / 256, 256, 0, stream>>>(outp, out, MROWS * CC / 4);
}

// Round 7
// 142.959 us; speedup vs baseline: 7.6045x; 1.0008x over previous
//
#include <hip/hip_runtime.h>
#include <hip/hip_bf16.h>
#include <math.h>

#define BB 2
#define TT 1024
#define CC 2048
#define NH 16
#define NKV 4
#define HD 128
#define MROWS 2048
#define QKVN 3072              // 2048 q + 512 k + 512 v
#define KOFF 2048
#define VOFF 2560

typedef unsigned short u16;
typedef unsigned int   u32;
typedef _Float16 f16;
typedef _Float16 f16x8 __attribute__((ext_vector_type(8)));
typedef short    s16x8 __attribute__((ext_vector_type(8)));
typedef float    f32x4 __attribute__((ext_vector_type(4)));

__device__ __forceinline__ u16 f2h(float f) {
    union { f16 h; u16 u; } x; x.h = (f16)f; return x.u;
}
__device__ __forceinline__ float h2f(u16 u) {
    union { u16 u; f16 h; } x; x.u = u; return (float)x.h;
}

#define GLDS(gp, lp) __builtin_amdgcn_global_load_lds( \
    (const __attribute__((address_space(1))) u32*)(gp), \
    (__attribute__((address_space(3))) u32*)(lp), 16, 0, 0)

// ---------------------------------------------------------------------------
// x fp32 -> fp16
// ---------------------------------------------------------------------------
__global__ void conv_x(const float* __restrict__ src, u16* __restrict__ dst, int n4) {
    int i = blockIdx.x * 256 + threadIdx.x;
    if (i >= n4) return;
    float4 v = ((const float4*)src)[i];
    ushort4 o;
    o.x = f2h(v.x); o.y = f2h(v.y); o.z = f2h(v.z); o.w = f2h(v.w);
    ((ushort4*)dst)[i] = o;
}

// ---------------------------------------------------------------------------
// Transpose-convert: Wt[row_off + n][k] = src[k][n]  (K=2048 fixed), fp16 out
// ---------------------------------------------------------------------------
__global__ __launch_bounds__(256) void conv_wT(const float* __restrict__ src,
                                               u16* __restrict__ Wt,
                                               int Nsrc, int row_off) {
    __shared__ float tile[32][33];
    const int k0 = blockIdx.x * 32;
    const int n0 = blockIdx.y * 32;
    const int t = threadIdx.x;
    const int r = t >> 3, c4 = (t & 7) * 4;
    float4 v = *(const float4*)&src[(size_t)(k0 + r) * Nsrc + n0 + c4];
    tile[r][c4 + 0] = v.x; tile[r][c4 + 1] = v.y;
    tile[r][c4 + 2] = v.z; tile[r][c4 + 3] = v.w;
    __syncthreads();
    ushort4 o;
    o.x = f2h(tile[c4 + 0][r]); o.y = f2h(tile[c4 + 1][r]);
    o.z = f2h(tile[c4 + 2][r]); o.w = f2h(tile[c4 + 3][r]);
    *(ushort4*)&Wt[(size_t)(row_off + n0 + r) * 2048 + k0 + c4] = o;
}

// ---------------------------------------------------------------------------
// RoPE + split-K reduce, vectorized: 4 pairs (16 B) per thread.
// ---------------------------------------------------------------------------
__global__ void rope_red(const u16* __restrict__ pp, u16* __restrict__ qkv,
                         const float* __restrict__ angles, int nq4, int ntot4) {
    const size_t PSZ = (size_t)MROWS * QKVN;
    int idx = blockIdx.x * 256 + threadIdx.x;
    if (idx >= ntot4) return;
    int p4, col, m;
    if (idx < nq4) {
        p4 = idx & 15; int rest = idx >> 4;
        int h = rest & 15; m = rest >> 4;
        col = h * 128 + p4 * 8;
    } else {
        int j = idx - nq4; p4 = j & 15; int rest = j >> 4;
        int h = rest & 3; m = rest >> 2;
        col = KOFF + h * 128 + p4 * 8;
    }
    size_t off = (size_t)m * QKVN + col;
    s16x8 a = *(const s16x8*)(pp + off);
    s16x8 b = *(const s16x8*)(pp + PSZ + off);
    int tpos = m & (TT - 1);
    float4 ang = *(const float4*)&angles[tpos * 64 + p4 * 4];
    float an[4] = {ang.x, ang.y, ang.z, ang.w};
    s16x8 o;
#pragma unroll
    for (int u = 0; u < 4; ++u) {
        float x0 = h2f((u16)a[2 * u])     + h2f((u16)b[2 * u]);
        float x1 = h2f((u16)a[2 * u + 1]) + h2f((u16)b[2 * u + 1]);
        float s = sinf(an[u]), c = cosf(an[u]);
        o[2 * u]     = (short)f2h(c * x0 - s * x1);
        o[2 * u + 1] = (short)f2h(s * x0 + c * x1);
    }
    *(s16x8*)(qkv + off) = o;
}

// ---------------------------------------------------------------------------
// V^T + split-K reduce: vtg[(b*NKV+hk)*128 + d][j] = p0.v + p1.v  (fp16)
// ---------------------------------------------------------------------------
__global__ __launch_bounds__(256) void vT_red(const u16* __restrict__ pp,
                                              u16* __restrict__ vtg) {
    const size_t PSZ = (size_t)MROWS * QKVN;
    __shared__ u16 tl[32][34];
    const int j0 = blockIdx.x * 32;
    const int d0 = blockIdx.y * 32;
    const int bhk = blockIdx.z;
    const int b = bhk >> 2, hk = bhk & 3;
    const int t = threadIdx.x;
    {
        int j_in = t >> 3, c4 = (t & 7) * 4;
        size_t off = (size_t)(b * TT + j0 + j_in) * QKVN + VOFF + hk * 128 + d0 + c4;
        ushort4 a = *(const ushort4*)(pp + off);
        ushort4 b4 = *(const ushort4*)(pp + PSZ + off);
        tl[j_in][c4 + 0] = f2h(h2f(a.x) + h2f(b4.x));
        tl[j_in][c4 + 1] = f2h(h2f(a.y) + h2f(b4.y));
        tl[j_in][c4 + 2] = f2h(h2f(a.z) + h2f(b4.z));
        tl[j_in][c4 + 3] = f2h(h2f(a.w) + h2f(b4.w));
    }
    __syncthreads();
    {
        int d_in = t >> 3, j4 = (t & 7) * 4;
        ushort4 o;
        o.x = tl[j4 + 0][d_in]; o.y = tl[j4 + 1][d_in];
        o.z = tl[j4 + 2][d_in]; o.w = tl[j4 + 3][d_in];
        *(ushort4*)&vtg[(size_t)(bhk * 128 + d0 + d_in) * 1024 + j0 + j4] = o;
    }
}

// ---------------------------------------------------------------------------
// fp16 MFMA GEMM v2: 128x128 tile, BK=64, 4 waves (2x2 of 64x64),
// double-buffered LDS (64 KB), one barrier per K-step, (row&7) XOR swizzle
// -> conflict-free ds_read_b128.  Split-K via blockIdx.z (klen multiple of 128).
// ---------------------------------------------------------------------------
template <int OUTB>
__global__ __launch_bounds__(256) void gemm_f16(const u16* __restrict__ A,
                                                const u16* __restrict__ Bt,
                                                float* __restrict__ Cf,
                                                u16* __restrict__ Cb,
                                                int M, int N, int K, int klen) {
    __shared__ __align__(16) u16 As0[128 * 64];
    __shared__ __align__(16) u16 As1[128 * 64];
    __shared__ __align__(16) u16 Bs0[128 * 64];
    __shared__ __align__(16) u16 Bs1[128 * 64];
    const int t = threadIdx.x;
    const int l = t & 63;
    const int w = t >> 6;
    const int row0 = blockIdx.y * 128;
    const int col0 = blockIdx.x * 128;
    const int koff = blockIdx.z * klen;
    const int wr = w >> 1, wc = w & 1;
    const int lg = l >> 4, ll = l & 15;

    f32x4 acc[4][4] = {};

// stage one 128x64 A-tile + B-tile into (AS,BS): wave w covers rows 32w..32w+31
// via 4 insts of 8 rows; LDS linear dest, source chunk pre-swizzled by row&7.
#define GSTAGE(AS, BS, k0v) do {                                              \
    _Pragma("unroll")                                                         \
    for (int e_ = 0; e_ < 4; ++e_) {                                          \
        int r_ = 32 * w + 8 * e_ + (l >> 3);                                  \
        int cg_ = (l & 7) ^ (r_ & 7);                                         \
        GLDS(A  + (size_t)(row0 + r_) * K + (k0v) + cg_ * 8,                  \
             (AS) + (32 * w + 8 * e_) * 64);                                  \
        GLDS(Bt + (size_t)(col0 + r_) * K + (k0v) + cg_ * 8,                  \
             (BS) + (32 * w + 8 * e_) * 64);                                  \
    }                                                                         \
} while (0)

#define GCOMP(AS, BS) do {                                                    \
    _Pragma("unroll")                                                         \
    for (int kc_ = 0; kc_ < 2; ++kc_) {                                       \
        f16x8 af_[4], bf_[4];                                                 \
        _Pragma("unroll")                                                     \
        for (int m_ = 0; m_ < 4; ++m_) {                                      \
            int row_ = wr * 64 + 16 * m_ + ll;                                \
            af_[m_] = *(const f16x8*)&(AS)[row_ * 64 +                        \
                        (((lg + 4 * kc_) ^ (ll & 7)) * 8)];                   \
            int col_ = wc * 64 + 16 * m_ + ll;                                \
            bf_[m_] = *(const f16x8*)&(BS)[col_ * 64 +                        \
                        (((lg + 4 * kc_) ^ (ll & 7)) * 8)];                   \
        }                                                                     \
        _Pragma("unroll")                                                     \
        for (int m_ = 0; m_ < 4; ++m_)                                        \
            _Pragma("unroll")                                                 \
            for (int n_ = 0; n_ < 4; ++n_)                                    \
                acc[m_][n_] = __builtin_amdgcn_mfma_f32_16x16x32_f16(         \
                    af_[m_], bf_[n_], acc[m_][n_], 0, 0, 0);                  \
    }                                                                         \
} while (0)

    const int n = klen >> 6;   // K-steps of 64; klen multiple of 128 -> n even
    GSTAGE(As0, Bs0, koff);
    __syncthreads();
#pragma unroll 1
    for (int i = 0; i < n; i += 2) {
        GSTAGE(As1, Bs1, koff + (i + 1) * 64);
        GCOMP(As0, Bs0);
        __syncthreads();
        if (i + 2 < n) GSTAGE(As0, Bs0, koff + (i + 2) * 64);
        GCOMP(As1, Bs1);
        __syncthreads();
    }
#undef GSTAGE
#undef GCOMP

    const size_t zoff = (size_t)blockIdx.z * M * N;
    const int orow = row0 + wr * 64 + lg * 4;
    const int ocol = col0 + wc * 64 + ll;
#pragma unroll
    for (int m = 0; m < 4; ++m)
#pragma unroll
        for (int nn = 0; nn < 4; ++nn)
#pragma unroll
            for (int r = 0; r < 4; ++r) {
                size_t off = zoff + (size_t)(orow + 16 * m + r) * N + ocol + 16 * nn;
                if (OUTB) Cb[off] = f2h(acc[m][nn][r]);
                else      Cf[off] = acc[m][nn][r];
            }
}

// ---------------------------------------------------------------------------
// out = p0 + p1 (fp32 elementwise)
// ---------------------------------------------------------------------------
__global__ void red_f32(const float* __restrict__ pp, float* __restrict__ out, int n4) {
    int i = blockIdx.x * 256 + threadIdx.x;
    if (i >= n4) return;
    const size_t PSZ = (size_t)MROWS * CC;
    float4 a = ((const float4*)pp)[i];
    float4 b = ((const float4*)(pp + PSZ))[i];
    ((float4*)out)[i] = make_float4(a.x + b.x, a.y + b.y, a.z + b.z, a.w + b.w);
}

// ---------------------------------------------------------------------------
// MFMA flash attention (swapped roles): triangle-paired blocks, double-buffered
// Q/Vt staging, defer-max rescale.  (unchanged from round 5)
// ---------------------------------------------------------------------------
__global__ __launch_bounds__(256) void attn_mfma(const u16* __restrict__ qkv,
                                                 const u16* __restrict__ vtg,
                                                 u16* __restrict__ attnb) {
    __shared__ __align__(16) u16 Qs0[64 * 128];
    __shared__ __align__(16) u16 Qs1[64 * 128];
    __shared__ __align__(16) u16 Vt0[128 * 64];
    __shared__ __align__(16) u16 Vt1[128 * 64];
    __shared__ __align__(16) u16 Ps[4 * 16 * 72];

    const int t = threadIdx.x, l = t & 63, w = t >> 6;
    const int bh = blockIdx.y;
    const int b = bh >> 4, h = bh & 15, hk = h & 3;
    const int lg = l >> 4, ll = l & 15;

    const u16* qbase = qkv + (size_t)(b * TT) * QKVN + h * 128;
    const u16* vbase = vtg + (size_t)((b * NKV + hk) * 128) * 1024;

    const int rq = 16 * w + (l >> 4);
    const int cq = l & 15;
    const int dv = 32 * w + (l >> 3);
    const int cv = l & 7;

#define STAGE(j0v, Qd, Vd) do {                                               \
    _Pragma("unroll")                                                         \
    for (int e_ = 0; e_ < 4; ++e_) {                                          \
        int r_ = rq + 4 * e_;                                                 \
        GLDS(qbase + (size_t)((j0v) + r_) * QKVN + ((cq ^ (r_ & 7)) * 8),     \
             (Qd) + (16 * w + 4 * e_) * 128);                                 \
    }                                                                         \
    _Pragma("unroll")                                                         \
    for (int e_ = 0; e_ < 4; ++e_) {                                          \
        int d_ = dv + 8 * e_;                                                 \
        GLDS(vbase + (size_t)d_ * 1024 + (j0v) + ((cv ^ (d_ & 7)) * 8),       \
             (Vd) + (32 * w + 8 * e_) * 64);                                  \
    }                                                                         \
} while (0)

#pragma unroll 1
    for (int ph = 0; ph < 2; ++ph) {
        const int it = ph ? (15 - blockIdx.x) : blockIdx.x;
        const int iw = it * 64 + w * 16;

        f16x8 kf[4];
        {
            const u16* kp = qkv + (size_t)(b * TT + iw + ll) * QKVN + KOFF + hk * 128 + lg * 8;
#pragma unroll
            for (int c = 0; c < 4; ++c) kf[c] = *(const f16x8*)(kp + 32 * c);
        }

        f32x4 o[8] = {};
        float mrun[4] = {-1e30f, -1e30f, -1e30f, -1e30f};
        float lrun[4] = {0.f, 0.f, 0.f, 0.f};

        const int nt = it + 1;
        STAGE(0, Qs0, Vt0);
        __syncthreads();

#pragma unroll 1
        for (int jt = 0; jt < nt; ++jt) {
            u16* Qc = (jt & 1) ? Qs1 : Qs0;
            u16* Vc = (jt & 1) ? Vt1 : Vt0;
            if (jt + 1 < nt) {
                u16* Qn = (jt & 1) ? Qs0 : Qs1;
                u16* Vn = (jt & 1) ? Vt0 : Vt1;
                STAGE((jt + 1) * 64, Qn, Vn);
            }

            f32x4 s[4] = {};
#pragma unroll
            for (int kc = 0; kc < 4; ++kc)
#pragma unroll
                for (int n = 0; n < 4; ++n) {
                    f16x8 qf = *(const f16x8*)&Qc[(16 * n + ll) * 128 + (((lg + 4 * kc) ^ (ll & 7)) * 8)];
                    s[n] = __builtin_amdgcn_mfma_f32_16x16x32_f16(kf[kc], qf, s[n], 0, 0, 0);
                }

            if (jt == it) {
#pragma unroll
                for (int n = 0; n < 4; ++n)
#pragma unroll
                    for (int r = 0; r < 4; ++r)
                        s[n][r] = (16 * n + ll <= 16 * w + 4 * lg + r) ? s[n][r] : -1e30f;
            }

            float tml[4];
            bool need = false;
#pragma unroll
            for (int r = 0; r < 4; ++r) {
                float tm = fmaxf(fmaxf(s[0][r], s[1][r]), fmaxf(s[2][r], s[3][r]));
                tml[r] = tm;
                need |= (tm > mrun[r] + 8.0f);
            }
            if (__any(need)) {
#pragma unroll
                for (int r = 0; r < 4; ++r) {
                    float tm = tml[r];
                    tm = fmaxf(tm, __shfl_xor(tm, 1, 16));
                    tm = fmaxf(tm, __shfl_xor(tm, 2, 16));
                    tm = fmaxf(tm, __shfl_xor(tm, 4, 16));
                    tm = fmaxf(tm, __shfl_xor(tm, 8, 16));
                    float mnew = fmaxf(mrun[r], tm);
                    float al = __expf(mrun[r] - mnew);
                    lrun[r] *= al;
                    mrun[r] = mnew;
#pragma unroll
                    for (int n = 0; n < 8; ++n) o[n][r] *= al;
                }
            }
            float p[4][4];
#pragma unroll
            for (int r = 0; r < 4; ++r) {
                float ps = 0.f;
#pragma unroll
                for (int n = 0; n < 4; ++n) { p[n][r] = __expf(s[n][r] - mrun[r]); ps += p[n][r]; }
                lrun[r] += ps;
            }

            u16* pw = Ps + w * (16 * 72);
#pragma unroll
            for (int n = 0; n < 4; ++n)
#pragma unroll
                for (int r = 0; r < 4; ++r)
                    pw[(4 * lg + r) * 72 + ll + 16 * n] = f2h(p[n][r]);
            f16x8 pa0 = *(const f16x8*)&pw[ll * 72 + 8 * lg];
            f16x8 pa1 = *(const f16x8*)&pw[ll * 72 + 8 * lg + 32];

#pragma unroll
            for (int n = 0; n < 8; ++n) {
                f16x8 vf0 = *(const f16x8*)&Vc[(16 * n + ll) * 64 + ((lg ^ (ll & 7)) * 8)];
                o[n] = __builtin_amdgcn_mfma_f32_16x16x32_f16(pa0, vf0, o[n], 0, 0, 0);
                f16x8 vf1 = *(const f16x8*)&Vc[(16 * n + ll) * 64 + (((lg + 4) ^ (ll & 7)) * 8)];
                o[n] = __builtin_amdgcn_mfma_f32_16x16x32_f16(pa1, vf1, o[n], 0, 0, 0);
            }

            __syncthreads();
        }

        u16* dst = attnb + (size_t)(b * TT + iw + 4 * lg) * CC + h * 128 + ll;
#pragma unroll
        for (int r = 0; r < 4; ++r) {
            float L = lrun[r];
            L += __shfl_xor(L, 1, 16);
            L += __shfl_xor(L, 2, 16);
            L += __shfl_xor(L, 4, 16);
            L += __shfl_xor(L, 8, 16);
            float inv = 1.0f / L;
#pragma unroll
            for (int n = 0; n < 8; ++n)
                dst[(size_t)r * CC + 16 * n] = f2h(o[n][r] * inv);
        }
    }
#undef STAGE
}

// ---------------------------------------------------------------------------
extern "C" void kernel_launch(void* const* d_in, const int* in_sizes, int n_in,
                              void* d_out, int out_size, void* d_ws, size_t ws_size,
                              hipStream_t stream) {
    const float* x      = (const float*)d_in[0];
    const float* angles = (const float*)d_in[1];
    const float* wq     = (const float*)d_in[2];
    const float* wk     = (const float*)d_in[3];
    const float* wv     = (const float*)d_in[4];
    const float* wo     = (const float*)d_in[5];
    float* out = (float*)d_out;

    char* ws = (char*)d_ws;
    u16*   Wt1   = (u16*)ws;                           // [0, 12.58M)
    u16*   vtg   = (u16*)(ws + 8388608);               // [8.39M, 10.49M) over Wt1 tail
    u16*   xb    = (u16*)(ws + 12582912);              // [12.58M, 20.97M) also attnb
    u16*   qkvb  = (u16*)(ws + 20971520);              // [20.97M, 33.55M)
    u16*   p01   = (u16*)(ws + 33554432);              // [33.55M, 58.72M) 2 fp16 partials
    float* outp  = (float*)(ws + 20971520);            // [20.97M, 54.53M) 2 fp32 partials
    u16*   attnb = xb;

    // 1. x -> fp16
    conv_x<<<(MROWS * CC / 4 + 255) / 256, 256, 0, stream>>>(x, xb, MROWS * CC / 4);
    // 2. weights -> Wt1 = [Wq;Wk;Wv]^T (3072 x 2048) fp16
    conv_wT<<<dim3(64, 64), 256, 0, stream>>>(wq, Wt1, CC,  0);
    conv_wT<<<dim3(64, 16), 256, 0, stream>>>(wk, Wt1, 512, 2048);
    conv_wT<<<dim3(64, 16), 256, 0, stream>>>(wv, Wt1, 512, 2560);
    // 3. fused QKV projection, split-K=2 -> p01 (fp16 partials)
    gemm_f16<1><<<dim3(QKVN / 128, MROWS / 128, 2), 256, 0, stream>>>(
        xb, Wt1, (float*)nullptr, p01, MROWS, QKVN, CC, 1024);
    // 4. reduce + RoPE (q,k) -> qkvb ; reduce + transpose (v) -> vtg
    {
        int nq4 = MROWS * NH * 16, nk4 = MROWS * NKV * 16;
        rope_red<<<(nq4 + nk4 + 255) / 256, 256, 0, stream>>>(p01, qkvb, angles, nq4, nq4 + nk4);
        vT_red<<<dim3(32, 4, 8), 256, 0, stream>>>(p01, vtg);
    }
    // 5. attention (paired-balanced, double-buffered) -> attnb (fp16)
    attn_mfma<<<dim3(8, BB * NH), 256, 0, stream>>>(qkvb, vtg, attnb);
    // 6. Wo^T -> Wt1 head, out projection split-K=2 -> fp32 partials, reduce
    conv_wT<<<dim3(64, 64), 256, 0, stream>>>(wo, Wt1, CC, 0);
    gemm_f16<0><<<dim3(CC / 128, MROWS / 128, 2), 256, 0, stream>>>(
        attnb, Wt1, outp, (u16*)nullptr, MROWS, CC, CC, 1024);
    red_f32<<<(MROWS * CC / 4 + 255) / 256, 256, 0, stream>>>(outp, out, MROWS * CC / 4);
}

// Round 8
// 125.314 us; speedup vs baseline: 8.6752x; 1.1408x over previous
//
#include <hip/hip_runtime.h>
#include <hip/hip_bf16.h>
#include <math.h>

#define BB 2
#define TT 1024
#define CC 2048
#define NH 16
#define NKV 4
#define HD 128
#define MROWS 2048
#define QKVN 3072              // 2048 q + 512 k + 512 v
#define KOFF 2048
#define VOFF 2560

typedef unsigned short u16;
typedef unsigned int   u32;
typedef _Float16 f16;
typedef _Float16 f16x8 __attribute__((ext_vector_type(8)));
typedef short    s16x8 __attribute__((ext_vector_type(8)));
typedef float    f32x4 __attribute__((ext_vector_type(4)));

__device__ __forceinline__ u16 f2h(float f) {
    union { f16 h; u16 u; } x; x.h = (f16)f; return x.u;
}
__device__ __forceinline__ float h2f(u16 u) {
    union { u16 u; f16 h; } x; x.u = u; return (float)x.h;
}

#define GLDS(gp, lp) __builtin_amdgcn_global_load_lds( \
    (const __attribute__((address_space(1))) u32*)(gp), \
    (__attribute__((address_space(3))) u32*)(lp), 16, 0, 0)

// ---------------------------------------------------------------------------
// prep: one launch for all conversions.
//   bid [0,4096):      x fp32 -> fp16 (xb)
//   bid [4096,8192):   wq^T  -> Wt1 rows 0..2047
//   bid [8192,9216):   wk^T  -> Wt1 rows 2048..2559
//   bid [9216,10240):  wv^T  -> Wt1 rows 2560..3071
//   bid [10240,14336): wo^T  -> Wt2
//   bid [14336,14592): cs[i] = (cos(angles[i]), sin(angles[i]))
// ---------------------------------------------------------------------------
__device__ __forceinline__ void wT_tile(const float* __restrict__ src,
                                        u16* __restrict__ Wt, int Nsrc,
                                        int row_off, int idx, int t,
                                        float tile[32][33]) {
    const int k0 = (idx & 63) * 32;
    const int n0 = (idx >> 6) * 32;
    const int r = t >> 3, c4 = (t & 7) * 4;
    float4 v = *(const float4*)&src[(size_t)(k0 + r) * Nsrc + n0 + c4];
    tile[r][c4 + 0] = v.x; tile[r][c4 + 1] = v.y;
    tile[r][c4 + 2] = v.z; tile[r][c4 + 3] = v.w;
    __syncthreads();
    ushort4 o;
    o.x = f2h(tile[c4 + 0][r]); o.y = f2h(tile[c4 + 1][r]);
    o.z = f2h(tile[c4 + 2][r]); o.w = f2h(tile[c4 + 3][r]);
    *(ushort4*)&Wt[(size_t)(row_off + n0 + r) * 2048 + k0 + c4] = o;
}

__global__ __launch_bounds__(256) void prep(const float* __restrict__ x,
                                            const float* __restrict__ wq,
                                            const float* __restrict__ wk,
                                            const float* __restrict__ wv,
                                            const float* __restrict__ wo,
                                            const float* __restrict__ angles,
                                            u16* __restrict__ xb,
                                            u16* __restrict__ Wt1,
                                            u16* __restrict__ Wt2,
                                            float2* __restrict__ cs) {
    __shared__ float tile[32][33];
    const int bid = blockIdx.x, t = threadIdx.x;
    if (bid < 4096) {                 // x -> fp16, 4 elems/thread
        int i = bid * 256 + t;
        float4 v = ((const float4*)x)[i];
        ushort4 o;
        o.x = f2h(v.x); o.y = f2h(v.y); o.z = f2h(v.z); o.w = f2h(v.w);
        ((ushort4*)xb)[i] = o;
    } else if (bid < 8192) {
        wT_tile(wq, Wt1, 2048, 0,    bid - 4096, t, tile);
    } else if (bid < 9216) {
        wT_tile(wk, Wt1, 512,  2048, bid - 8192, t, tile);
    } else if (bid < 10240) {
        wT_tile(wv, Wt1, 512,  2560, bid - 9216, t, tile);
    } else if (bid < 14336) {
        wT_tile(wo, Wt2, 2048, 0,    bid - 10240, t, tile);
    } else {
        int i = (bid - 14336) * 256 + t;   // < 65536
        float a = angles[i];
        cs[i] = make_float2(cosf(a), sinf(a));
    }
}

// ---------------------------------------------------------------------------
// gemm_qkv: [2048 x 2048] @ [3072 x 2048]^T, 128x96 tiles -> 512 blocks (2/CU,
// perfectly balanced), full K, BK=64 double-buffered, (row&7) XOR swizzle.
// Fused epilogue: q/k cols -> RoPE (shfl pair + cs table) -> qkv; v cols ->
// transposed ushort4 writes -> vtg.
// ---------------------------------------------------------------------------
__global__ __launch_bounds__(256) void gemm_qkv(const u16* __restrict__ A,
                                                const u16* __restrict__ Bt,
                                                u16* __restrict__ qkv,
                                                u16* __restrict__ vtg,
                                                const float2* __restrict__ cs) {
    __shared__ __align__(16) u16 As0[128 * 64];
    __shared__ __align__(16) u16 As1[128 * 64];
    __shared__ __align__(16) u16 Bs0[96 * 64];
    __shared__ __align__(16) u16 Bs1[96 * 64];
    const int t = threadIdx.x, l = t & 63, w = t >> 6;
    const int row0 = blockIdx.y * 128;   // 16 row-tiles
    const int col0 = blockIdx.x * 96;    // 32 col-tiles
    const int wr = w >> 1, wc = w & 1;
    const int lg = l >> 4, ll = l & 15;
    const int K = 2048;

    f32x4 acc[4][3] = {};

#define QSTAGE(AS, BS, k0v) do {                                              \
    _Pragma("unroll")                                                         \
    for (int e_ = 0; e_ < 4; ++e_) {                                          \
        int r_ = 32 * w + 8 * e_ + (l >> 3);                                  \
        int cg_ = (l & 7) ^ (r_ & 7);                                         \
        GLDS(A + (size_t)(row0 + r_) * K + (k0v) + cg_ * 8,                   \
             (AS) + (32 * w + 8 * e_) * 64);                                  \
    }                                                                         \
    _Pragma("unroll")                                                         \
    for (int e_ = 0; e_ < 3; ++e_) {                                          \
        int r_ = 24 * w + 8 * e_ + (l >> 3);                                  \
        int cg_ = (l & 7) ^ (r_ & 7);                                         \
        GLDS(Bt + (size_t)(col0 + r_) * K + (k0v) + cg_ * 8,                  \
             (BS) + (24 * w + 8 * e_) * 64);                                  \
    }                                                                         \
} while (0)

#define QCOMP(AS, BS) do {                                                    \
    _Pragma("unroll")                                                         \
    for (int kc_ = 0; kc_ < 2; ++kc_) {                                       \
        f16x8 af_[4], bf_[3];                                                 \
        _Pragma("unroll")                                                     \
        for (int m_ = 0; m_ < 4; ++m_) {                                      \
            int row_ = wr * 64 + 16 * m_ + ll;                                \
            af_[m_] = *(const f16x8*)&(AS)[row_ * 64 +                        \
                        (((lg + 4 * kc_) ^ (ll & 7)) * 8)];                   \
        }                                                                     \
        _Pragma("unroll")                                                     \
        for (int n_ = 0; n_ < 3; ++n_) {                                      \
            int col_ = wc * 48 + 16 * n_ + ll;                                \
            bf_[n_] = *(const f16x8*)&(BS)[col_ * 64 +                        \
                        (((lg + 4 * kc_) ^ (ll & 7)) * 8)];                   \
        }                                                                     \
        _Pragma("unroll")                                                     \
        for (int m_ = 0; m_ < 4; ++m_)                                        \
            _Pragma("unroll")                                                 \
            for (int n_ = 0; n_ < 3; ++n_)                                    \
                acc[m_][n_] = __builtin_amdgcn_mfma_f32_16x16x32_f16(         \
                    af_[m_], bf_[n_], acc[m_][n_], 0, 0, 0);                  \
    }                                                                         \
} while (0)

    QSTAGE(As0, Bs0, 0);
    __syncthreads();
#pragma unroll 1
    for (int i = 0; i < 32; i += 2) {
        QSTAGE(As1, Bs1, (i + 1) * 64);
        QCOMP(As0, Bs0);
        __syncthreads();
        if (i + 2 < 32) QSTAGE(As0, Bs0, (i + 2) * 64);
        QCOMP(As1, Bs1);
        __syncthreads();
    }
#undef QSTAGE
#undef QCOMP

    // fused epilogue
    const int orow = row0 + wr * 64 + lg * 4;
    const int ocol = col0 + wc * 48 + ll;
#pragma unroll
    for (int n = 0; n < 3; ++n) {
        const int col = ocol + 16 * n;
        if (col < VOFF) {
            // RoPE: pair (even,odd) cols live in adjacent lanes (col parity == ll parity)
            const int p = (col & 127) >> 1;
            const bool odd = ll & 1;
#pragma unroll
            for (int m = 0; m < 4; ++m) {
#pragma unroll
                for (int r = 0; r < 4; ++r) {
                    float v = acc[m][n][r];
                    float pr = __shfl_xor(v, 1);
                    int row = orow + 16 * m + r;
                    float2 a = cs[(row & (TT - 1)) * 64 + p];
                    float res = odd ? (a.y * pr + a.x * v) : (a.x * v - a.y * pr);
                    qkv[(size_t)row * QKVN + col] = f2h(res);
                }
            }
        } else {
            // V: write transposed, 4 consecutive j per ushort4
            int d = col - VOFF;
            const int hk = d >> 7; d &= 127;
            const int bb = orow >> 10;        // block rows never straddle b
            const int base_j = orow & (TT - 1);
#pragma unroll
            for (int m = 0; m < 4; ++m) {
                ushort4 pk;
                pk.x = f2h(acc[m][n][0]); pk.y = f2h(acc[m][n][1]);
                pk.z = f2h(acc[m][n][2]); pk.w = f2h(acc[m][n][3]);
                *(ushort4*)&vtg[((size_t)(bb * NKV + hk) * 128 + d) * 1024 + base_j + 16 * m] = pk;
            }
        }
    }
}

// ---------------------------------------------------------------------------
// gemm_out: [2048x2048] @ [2048x2048]^T, 128x128 tiles, BK=64 dbuf, split-K=2
// (512 blocks = 2/CU), fp16 partials (error ~4e-4, well under threshold).
// ---------------------------------------------------------------------------
__global__ __launch_bounds__(256) void gemm_out(const u16* __restrict__ A,
                                                const u16* __restrict__ Bt,
                                                u16* __restrict__ Cb) {
    __shared__ __align__(16) u16 As0[128 * 64];
    __shared__ __align__(16) u16 As1[128 * 64];
    __shared__ __align__(16) u16 Bs0[128 * 64];
    __shared__ __align__(16) u16 Bs1[128 * 64];
    const int t = threadIdx.x, l = t & 63, w = t >> 6;
    const int row0 = blockIdx.y * 128;
    const int col0 = blockIdx.x * 128;
    const int koff = blockIdx.z * 1024;
    const int wr = w >> 1, wc = w & 1;
    const int lg = l >> 4, ll = l & 15;
    const int K = 2048;

    f32x4 acc[4][4] = {};

#define GSTAGE(AS, BS, k0v) do {                                              \
    _Pragma("unroll")                                                         \
    for (int e_ = 0; e_ < 4; ++e_) {                                          \
        int r_ = 32 * w + 8 * e_ + (l >> 3);                                  \
        int cg_ = (l & 7) ^ (r_ & 7);                                         \
        GLDS(A  + (size_t)(row0 + r_) * K + (k0v) + cg_ * 8,                  \
             (AS) + (32 * w + 8 * e_) * 64);                                  \
        GLDS(Bt + (size_t)(col0 + r_) * K + (k0v) + cg_ * 8,                  \
             (BS) + (32 * w + 8 * e_) * 64);                                  \
    }                                                                         \
} while (0)

#define GCOMP(AS, BS) do {                                                    \
    _Pragma("unroll")                                                         \
    for (int kc_ = 0; kc_ < 2; ++kc_) {                                       \
        f16x8 af_[4], bf_[4];                                                 \
        _Pragma("unroll")                                                     \
        for (int m_ = 0; m_ < 4; ++m_) {                                      \
            int row_ = wr * 64 + 16 * m_ + ll;                                \
            af_[m_] = *(const f16x8*)&(AS)[row_ * 64 +                        \
                        (((lg + 4 * kc_) ^ (ll & 7)) * 8)];                   \
            int col_ = wc * 64 + 16 * m_ + ll;                                \
            bf_[m_] = *(const f16x8*)&(BS)[col_ * 64 +                        \
                        (((lg + 4 * kc_) ^ (ll & 7)) * 8)];                   \
        }                                                                     \
        _Pragma("unroll")                                                     \
        for (int m_ = 0; m_ < 4; ++m_)                                        \
            _Pragma("unroll")                                                 \
            for (int n_ = 0; n_ < 4; ++n_)                                    \
                acc[m_][n_] = __builtin_amdgcn_mfma_f32_16x16x32_f16(         \
                    af_[m_], bf_[n_], acc[m_][n_], 0, 0, 0);                  \
    }                                                                         \
} while (0)

    GSTAGE(As0, Bs0, koff);
    __syncthreads();
#pragma unroll 1
    for (int i = 0; i < 16; i += 2) {
        GSTAGE(As1, Bs1, koff + (i + 1) * 64);
        GCOMP(As0, Bs0);
        __syncthreads();
        if (i + 2 < 16) GSTAGE(As0, Bs0, koff + (i + 2) * 64);
        GCOMP(As1, Bs1);
        __syncthreads();
    }
#undef GSTAGE
#undef GCOMP

    const size_t zoff = (size_t)blockIdx.z * MROWS * CC;
    const int orow = row0 + wr * 64 + lg * 4;
    const int ocol = col0 + wc * 64 + ll;
#pragma unroll
    for (int m = 0; m < 4; ++m)
#pragma unroll
        for (int nn = 0; nn < 4; ++nn)
#pragma unroll
            for (int r = 0; r < 4; ++r)
                Cb[zoff + (size_t)(orow + 16 * m + r) * CC + ocol + 16 * nn] =
                    f2h(acc[m][nn][r]);
}

// ---------------------------------------------------------------------------
// red_out: out = h2f(p0) + h2f(p1), fp32.  8 elems/thread.
// ---------------------------------------------------------------------------
__global__ void red_out(const u16* __restrict__ pp, float* __restrict__ out, int n8) {
    int i = blockIdx.x * 256 + threadIdx.x;
    if (i >= n8) return;
    const size_t PSZ = (size_t)MROWS * CC;
    s16x8 a = ((const s16x8*)pp)[i];
    s16x8 b = ((const s16x8*)(pp + PSZ))[i];
    float4 o0, o1;
    o0.x = h2f((u16)a[0]) + h2f((u16)b[0]);
    o0.y = h2f((u16)a[1]) + h2f((u16)b[1]);
    o0.z = h2f((u16)a[2]) + h2f((u16)b[2]);
    o0.w = h2f((u16)a[3]) + h2f((u16)b[3]);
    o1.x = h2f((u16)a[4]) + h2f((u16)b[4]);
    o1.y = h2f((u16)a[5]) + h2f((u16)b[5]);
    o1.z = h2f((u16)a[6]) + h2f((u16)b[6]);
    o1.w = h2f((u16)a[7]) + h2f((u16)b[7]);
    ((float4*)out)[2 * i]     = o0;
    ((float4*)out)[2 * i + 1] = o1;
}

// ---------------------------------------------------------------------------
// MFMA flash attention (swapped roles): triangle-paired blocks, double-buffered
// Q/Vt staging, defer-max rescale.  (unchanged from round 7)
// ---------------------------------------------------------------------------
__global__ __launch_bounds__(256) void attn_mfma(const u16* __restrict__ qkv,
                                                 const u16* __restrict__ vtg,
                                                 u16* __restrict__ attnb) {
    __shared__ __align__(16) u16 Qs0[64 * 128];
    __shared__ __align__(16) u16 Qs1[64 * 128];
    __shared__ __align__(16) u16 Vt0[128 * 64];
    __shared__ __align__(16) u16 Vt1[128 * 64];
    __shared__ __align__(16) u16 Ps[4 * 16 * 72];

    const int t = threadIdx.x, l = t & 63, w = t >> 6;
    const int bh = blockIdx.y;
    const int b = bh >> 4, h = bh & 15, hk = h & 3;
    const int lg = l >> 4, ll = l & 15;

    const u16* qbase = qkv + (size_t)(b * TT) * QKVN + h * 128;
    const u16* vbase = vtg + (size_t)((b * NKV + hk) * 128) * 1024;

    const int rq = 16 * w + (l >> 4);
    const int cq = l & 15;
    const int dv = 32 * w + (l >> 3);
    const int cv = l & 7;

#define STAGE(j0v, Qd, Vd) do {                                               \
    _Pragma("unroll")                                                         \
    for (int e_ = 0; e_ < 4; ++e_) {                                          \
        int r_ = rq + 4 * e_;                                                 \
        GLDS(qbase + (size_t)((j0v) + r_) * QKVN + ((cq ^ (r_ & 7)) * 8),     \
             (Qd) + (16 * w + 4 * e_) * 128);                                 \
    }                                                                         \
    _Pragma("unroll")                                                         \
    for (int e_ = 0; e_ < 4; ++e_) {                                          \
        int d_ = dv + 8 * e_;                                                 \
        GLDS(vbase + (size_t)d_ * 1024 + (j0v) + ((cv ^ (d_ & 7)) * 8),       \
             (Vd) + (32 * w + 8 * e_) * 64);                                  \
    }                                                                         \
} while (0)

#pragma unroll 1
    for (int ph = 0; ph < 2; ++ph) {
        const int it = ph ? (15 - blockIdx.x) : blockIdx.x;
        const int iw = it * 64 + w * 16;

        f16x8 kf[4];
        {
            const u16* kp = qkv + (size_t)(b * TT + iw + ll) * QKVN + KOFF + hk * 128 + lg * 8;
#pragma unroll
            for (int c = 0; c < 4; ++c) kf[c] = *(const f16x8*)(kp + 32 * c);
        }

        f32x4 o[8] = {};
        float mrun[4] = {-1e30f, -1e30f, -1e30f, -1e30f};
        float lrun[4] = {0.f, 0.f, 0.f, 0.f};

        const int nt = it + 1;
        STAGE(0, Qs0, Vt0);
        __syncthreads();

#pragma unroll 1
        for (int jt = 0; jt < nt; ++jt) {
            u16* Qc = (jt & 1) ? Qs1 : Qs0;
            u16* Vc = (jt & 1) ? Vt1 : Vt0;
            if (jt + 1 < nt) {
                u16* Qn = (jt & 1) ? Qs0 : Qs1;
                u16* Vn = (jt & 1) ? Vt0 : Vt1;
                STAGE((jt + 1) * 64, Qn, Vn);
            }

            f32x4 s[4] = {};
#pragma unroll
            for (int kc = 0; kc < 4; ++kc)
#pragma unroll
                for (int n = 0; n < 4; ++n) {
                    f16x8 qf = *(const f16x8*)&Qc[(16 * n + ll) * 128 + (((lg + 4 * kc) ^ (ll & 7)) * 8)];
                    s[n] = __builtin_amdgcn_mfma_f32_16x16x32_f16(kf[kc], qf, s[n], 0, 0, 0);
                }

            if (jt == it) {
#pragma unroll
                for (int n = 0; n < 4; ++n)
#pragma unroll
                    for (int r = 0; r < 4; ++r)
                        s[n][r] = (16 * n + ll <= 16 * w + 4 * lg + r) ? s[n][r] : -1e30f;
            }

            float tml[4];
            bool need = false;
#pragma unroll
            for (int r = 0; r < 4; ++r) {
                float tm = fmaxf(fmaxf(s[0][r], s[1][r]), fmaxf(s[2][r], s[3][r]));
                tml[r] = tm;
                need |= (tm > mrun[r] + 8.0f);
            }
            if (__any(need)) {
#pragma unroll
                for (int r = 0; r < 4; ++r) {
                    float tm = tml[r];
                    tm = fmaxf(tm, __shfl_xor(tm, 1, 16));
                    tm = fmaxf(tm, __shfl_xor(tm, 2, 16));
                    tm = fmaxf(tm, __shfl_xor(tm, 4, 16));
                    tm = fmaxf(tm, __shfl_xor(tm, 8, 16));
                    float mnew = fmaxf(mrun[r], tm);
                    float al = __expf(mrun[r] - mnew);
                    lrun[r] *= al;
                    mrun[r] = mnew;
#pragma unroll
                    for (int n = 0; n < 8; ++n) o[n][r] *= al;
                }
            }
            float p[4][4];
#pragma unroll
            for (int r = 0; r < 4; ++r) {
                float ps = 0.f;
#pragma unroll
                for (int n = 0; n < 4; ++n) { p[n][r] = __expf(s[n][r] - mrun[r]); ps += p[n][r]; }
                lrun[r] += ps;
            }

            u16* pw = Ps + w * (16 * 72);
#pragma unroll
            for (int n = 0; n < 4; ++n)
#pragma unroll
                for (int r = 0; r < 4; ++r)
                    pw[(4 * lg + r) * 72 + ll + 16 * n] = f2h(p[n][r]);
            f16x8 pa0 = *(const f16x8*)&pw[ll * 72 + 8 * lg];
            f16x8 pa1 = *(const f16x8*)&pw[ll * 72 + 8 * lg + 32];

#pragma unroll
            for (int n = 0; n < 8; ++n) {
                f16x8 vf0 = *(const f16x8*)&Vc[(16 * n + ll) * 64 + ((lg ^ (ll & 7)) * 8)];
                o[n] = __builtin_amdgcn_mfma_f32_16x16x32_f16(pa0, vf0, o[n], 0, 0, 0);
                f16x8 vf1 = *(const f16x8*)&Vc[(16 * n + ll) * 64 + (((lg + 4) ^ (ll & 7)) * 8)];
                o[n] = __builtin_amdgcn_mfma_f32_16x16x32_f16(pa1, vf1, o[n], 0, 0, 0);
            }

            __syncthreads();
        }

        u16* dst = attnb + (size_t)(b * TT + iw + 4 * lg) * CC + h * 128 + ll;
#pragma unroll
        for (int r = 0; r < 4; ++r) {
            float L = lrun[r];
            L += __shfl_xor(L, 1, 16);
            L += __shfl_xor(L, 2, 16);
            L += __shfl_xor(L, 4, 16);
            L += __shfl_xor(L, 8, 16);
            float inv = 1.0f / L;
#pragma unroll
            for (int n = 0; n < 8; ++n)
                dst[(size_t)r * CC + 16 * n] = f2h(o[n][r] * inv);
        }
    }
#undef STAGE
}

// ---------------------------------------------------------------------------
extern "C" void kernel_launch(void* const* d_in, const int* in_sizes, int n_in,
                              void* d_out, int out_size, void* d_ws, size_t ws_size,
                              hipStream_t stream) {
    const float* x      = (const float*)d_in[0];
    const float* angles = (const float*)d_in[1];
    const float* wq     = (const float*)d_in[2];
    const float* wk     = (const float*)d_in[3];
    const float* wv     = (const float*)d_in[4];
    const float* wo     = (const float*)d_in[5];
    float* out = (float*)d_out;

    char* ws = (char*)d_ws;
    // layout (bytes):
    u16*    Wt1   = (u16*)ws;                         // [0, 12.58M)  qkv weights^T
    u16*    Wt2   = (u16*)(ws + 12582912);            // [12.58M, 20.97M)  wo^T
    float2* cs    = (float2*)(ws + 20971520);         // [20.97M, 21.5M)   sincos table
    u16*    xb    = (u16*)(ws + 21495808);            // [21.5M, 29.9M)
    u16*    qkvb  = (u16*)(ws + 29884416);            // [29.9M, 42.5M)  q,k regions
    u16*    vtg   = (u16*)(ws + 42467328);            // [42.5M, 44.6M)  V^T
    u16*    attnb = (u16*)(ws + 44564480);            // [44.6M, 53.0M)
    u16*    p01   = (u16*)(ws + 21495808);            // [21.5M, 38.3M) over xb/qkvb (dead)

    // 1. all conversions + sincos table (one launch)
    prep<<<14592, 256, 0, stream>>>(x, wq, wk, wv, wo, angles, xb, Wt1, Wt2, cs);
    // 2. QKV projection, full-K, fused RoPE + V^T epilogue
    gemm_qkv<<<dim3(32, 16), 256, 0, stream>>>(xb, Wt1, qkvb, vtg, cs);
    // 3. attention (paired-balanced, double-buffered)
    attn_mfma<<<dim3(8, BB * NH), 256, 0, stream>>>(qkvb, vtg, attnb);
    // 4. output projection, split-K=2, fp16 partials
    gemm_out<<<dim3(16, 16, 2), 256, 0, stream>>>(attnb, Wt2, p01);
    // 5. reduce partials -> fp32 out
    red_out<<<2048, 256, 0, stream>>>(p01, out, MROWS * CC / 8);
}

// Round 9
// 116.735 us; speedup vs baseline: 9.3128x; 1.0735x over previous
//
#include <hip/hip_runtime.h>
#include <hip/hip_bf16.h>
#include <math.h>

#define BB 2
#define TT 1024
#define CC 2048
#define NH 16
#define NKV 4
#define HD 128
#define MROWS 2048
#define QKVN 3072              // 2048 q + 512 k + 512 v
#define KOFF 2048
#define VOFF 2560

typedef unsigned short u16;
typedef unsigned int   u32;
typedef _Float16 f16;
typedef _Float16 f16x8 __attribute__((ext_vector_type(8)));
typedef short    s16x8 __attribute__((ext_vector_type(8)));
typedef float    f32x4 __attribute__((ext_vector_type(4)));

__device__ __forceinline__ u16 f2h(float f) {
    union { f16 h; u16 u; } x; x.h = (f16)f; return x.u;
}
__device__ __forceinline__ float h2f(u16 u) {
    union { u16 u; f16 h; } x; x.u = u; return (float)x.h;
}

#define GLDS(gp, lp) __builtin_amdgcn_global_load_lds( \
    (const __attribute__((address_space(1))) u32*)(gp), \
    (__attribute__((address_space(3))) u32*)(lp), 16, 0, 0)

// ---------------------------------------------------------------------------
// prep: one launch for all conversions (x->f16, 4x W^T, sincos table).
// ---------------------------------------------------------------------------
__device__ __forceinline__ void wT_tile(const float* __restrict__ src,
                                        u16* __restrict__ Wt, int Nsrc,
                                        int row_off, int idx, int t,
                                        float tile[32][33]) {
    const int k0 = (idx & 63) * 32;
    const int n0 = (idx >> 6) * 32;
    const int r = t >> 3, c4 = (t & 7) * 4;
    float4 v = *(const float4*)&src[(size_t)(k0 + r) * Nsrc + n0 + c4];
    tile[r][c4 + 0] = v.x; tile[r][c4 + 1] = v.y;
    tile[r][c4 + 2] = v.z; tile[r][c4 + 3] = v.w;
    __syncthreads();
    ushort4 o;
    o.x = f2h(tile[c4 + 0][r]); o.y = f2h(tile[c4 + 1][r]);
    o.z = f2h(tile[c4 + 2][r]); o.w = f2h(tile[c4 + 3][r]);
    *(ushort4*)&Wt[(size_t)(row_off + n0 + r) * 2048 + k0 + c4] = o;
}

__global__ __launch_bounds__(256) void prep(const float* __restrict__ x,
                                            const float* __restrict__ wq,
                                            const float* __restrict__ wk,
                                            const float* __restrict__ wv,
                                            const float* __restrict__ wo,
                                            const float* __restrict__ angles,
                                            u16* __restrict__ xb,
                                            u16* __restrict__ Wt1,
                                            u16* __restrict__ Wt2,
                                            float2* __restrict__ cs) {
    __shared__ float tile[32][33];
    const int bid = blockIdx.x, t = threadIdx.x;
    if (bid < 4096) {                 // x -> fp16, 4 elems/thread
        int i = bid * 256 + t;
        float4 v = ((const float4*)x)[i];
        ushort4 o;
        o.x = f2h(v.x); o.y = f2h(v.y); o.z = f2h(v.z); o.w = f2h(v.w);
        ((ushort4*)xb)[i] = o;
    } else if (bid < 8192) {
        wT_tile(wq, Wt1, 2048, 0,    bid - 4096, t, tile);
    } else if (bid < 9216) {
        wT_tile(wk, Wt1, 512,  2048, bid - 8192, t, tile);
    } else if (bid < 10240) {
        wT_tile(wv, Wt1, 512,  2560, bid - 9216, t, tile);
    } else if (bid < 14336) {
        wT_tile(wo, Wt2, 2048, 0,    bid - 10240, t, tile);
    } else {
        int i = (bid - 14336) * 256 + t;   // < 65536
        float a = angles[i];
        cs[i] = make_float2(cosf(a), sinf(a));
    }
}

// ---------------------------------------------------------------------------
// gemm_qkv: [2048 x 2048] @ [3072 x 2048]^T, 128x96 tiles -> 512 blocks (2/CU,
// perfectly balanced), full K, BK=64 double-buffered, (row&7) XOR swizzle.
// Fused epilogue: q/k cols -> RoPE (shfl pair + cs table) -> qkv; v cols ->
// transposed ushort4 writes -> vtg.
// ---------------------------------------------------------------------------
__global__ __launch_bounds__(256) void gemm_qkv(const u16* __restrict__ A,
                                                const u16* __restrict__ Bt,
                                                u16* __restrict__ qkv,
                                                u16* __restrict__ vtg,
                                                const float2* __restrict__ cs) {
    __shared__ __align__(16) u16 As0[128 * 64];
    __shared__ __align__(16) u16 As1[128 * 64];
    __shared__ __align__(16) u16 Bs0[96 * 64];
    __shared__ __align__(16) u16 Bs1[96 * 64];
    const int t = threadIdx.x, l = t & 63, w = t >> 6;
    const int row0 = blockIdx.y * 128;   // 16 row-tiles
    const int col0 = blockIdx.x * 96;    // 32 col-tiles
    const int wr = w >> 1, wc = w & 1;
    const int lg = l >> 4, ll = l & 15;
    const int K = 2048;

    f32x4 acc[4][3] = {};

#define QSTAGE(AS, BS, k0v) do {                                              \
    _Pragma("unroll")                                                         \
    for (int e_ = 0; e_ < 4; ++e_) {                                          \
        int r_ = 32 * w + 8 * e_ + (l >> 3);                                  \
        int cg_ = (l & 7) ^ (r_ & 7);                                         \
        GLDS(A + (size_t)(row0 + r_) * K + (k0v) + cg_ * 8,                   \
             (AS) + (32 * w + 8 * e_) * 64);                                  \
    }                                                                         \
    _Pragma("unroll")                                                         \
    for (int e_ = 0; e_ < 3; ++e_) {                                          \
        int r_ = 24 * w + 8 * e_ + (l >> 3);                                  \
        int cg_ = (l & 7) ^ (r_ & 7);                                         \
        GLDS(Bt + (size_t)(col0 + r_) * K + (k0v) + cg_ * 8,                  \
             (BS) + (24 * w + 8 * e_) * 64);                                  \
    }                                                                         \
} while (0)

#define QCOMP(AS, BS) do {                                                    \
    _Pragma("unroll")                                                         \
    for (int kc_ = 0; kc_ < 2; ++kc_) {                                       \
        f16x8 af_[4], bf_[3];                                                 \
        _Pragma("unroll")                                                     \
        for (int m_ = 0; m_ < 4; ++m_) {                                      \
            int row_ = wr * 64 + 16 * m_ + ll;                                \
            af_[m_] = *(const f16x8*)&(AS)[row_ * 64 +                        \
                        (((lg + 4 * kc_) ^ (ll & 7)) * 8)];                   \
        }                                                                     \
        _Pragma("unroll")                                                     \
        for (int n_ = 0; n_ < 3; ++n_) {                                      \
            int col_ = wc * 48 + 16 * n_ + ll;                                \
            bf_[n_] = *(const f16x8*)&(BS)[col_ * 64 +                        \
                        (((lg + 4 * kc_) ^ (ll & 7)) * 8)];                   \
        }                                                                     \
        _Pragma("unroll")                                                     \
        for (int m_ = 0; m_ < 4; ++m_)                                        \
            _Pragma("unroll")                                                 \
            for (int n_ = 0; n_ < 3; ++n_)                                    \
                acc[m_][n_] = __builtin_amdgcn_mfma_f32_16x16x32_f16(         \
                    af_[m_], bf_[n_], acc[m_][n_], 0, 0, 0);                  \
    }                                                                         \
} while (0)

    QSTAGE(As0, Bs0, 0);
    __syncthreads();
#pragma unroll 1
    for (int i = 0; i < 32; i += 2) {
        QSTAGE(As1, Bs1, (i + 1) * 64);
        QCOMP(As0, Bs0);
        __syncthreads();
        if (i + 2 < 32) QSTAGE(As0, Bs0, (i + 2) * 64);
        QCOMP(As1, Bs1);
        __syncthreads();
    }
#undef QSTAGE
#undef QCOMP

    // fused epilogue
    const int orow = row0 + wr * 64 + lg * 4;
    const int ocol = col0 + wc * 48 + ll;
#pragma unroll
    for (int n = 0; n < 3; ++n) {
        const int col = ocol + 16 * n;
        if (col < VOFF) {
            // RoPE: pair (even,odd) cols live in adjacent lanes (col parity == ll parity)
            const int p = (col & 127) >> 1;
            const bool odd = ll & 1;
#pragma unroll
            for (int m = 0; m < 4; ++m) {
#pragma unroll
                for (int r = 0; r < 4; ++r) {
                    float v = acc[m][n][r];
                    float pr = __shfl_xor(v, 1);
                    int row = orow + 16 * m + r;
                    float2 a = cs[(row & (TT - 1)) * 64 + p];
                    float res = odd ? (a.y * pr + a.x * v) : (a.x * v - a.y * pr);
                    qkv[(size_t)row * QKVN + col] = f2h(res);
                }
            }
        } else {
            // V: write transposed, 4 consecutive j per ushort4
            int d = col - VOFF;
            const int hk = d >> 7; d &= 127;
            const int bb = orow >> 10;        // block rows never straddle b
            const int base_j = orow & (TT - 1);
#pragma unroll
            for (int m = 0; m < 4; ++m) {
                ushort4 pk;
                pk.x = f2h(acc[m][n][0]); pk.y = f2h(acc[m][n][1]);
                pk.z = f2h(acc[m][n][2]); pk.w = f2h(acc[m][n][3]);
                *(ushort4*)&vtg[((size_t)(bb * NKV + hk) * 128 + d) * 1024 + base_j + 16 * m] = pk;
            }
        }
    }
}

// ---------------------------------------------------------------------------
// gemm_out v2: [2048x2048] @ [2048x2048]^T, 128x128 tile, full K, 8 waves
// (512 thr, wave grid 2x4, 64x32 out/wave), BK=64 dbuf, fp32 direct out.
// 256 blocks = 1/CU (perfect balance), 2 waves/SIMD — same occupancy as the
// old split-K=2 variant without 50 MB of partial round-trip + extra kernel.
// ---------------------------------------------------------------------------
__global__ __launch_bounds__(512) void gemm_out(const u16* __restrict__ A,
                                                const u16* __restrict__ Bt,
                                                float* __restrict__ Cf) {
    __shared__ __align__(16) u16 As0[128 * 64];
    __shared__ __align__(16) u16 As1[128 * 64];
    __shared__ __align__(16) u16 Bs0[128 * 64];
    __shared__ __align__(16) u16 Bs1[128 * 64];
    const int t = threadIdx.x, l = t & 63, w = t >> 6;
    const int row0 = blockIdx.y * 128;
    const int col0 = blockIdx.x * 128;
    const int wr = w >> 2, wc = w & 3;   // 2x4 wave grid
    const int lg = l >> 4, ll = l & 15;
    const int K = 2048;

    f32x4 acc[4][2] = {};

#define GSTAGE(AS, BS, k0v) do {                                              \
    _Pragma("unroll")                                                         \
    for (int e_ = 0; e_ < 2; ++e_) {                                          \
        int r_ = 16 * w + 8 * e_ + (l >> 3);                                  \
        int cg_ = (l & 7) ^ (r_ & 7);                                         \
        GLDS(A  + (size_t)(row0 + r_) * K + (k0v) + cg_ * 8,                  \
             (AS) + (16 * w + 8 * e_) * 64);                                  \
        GLDS(Bt + (size_t)(col0 + r_) * K + (k0v) + cg_ * 8,                  \
             (BS) + (16 * w + 8 * e_) * 64);                                  \
    }                                                                         \
} while (0)

#define GCOMP(AS, BS) do {                                                    \
    _Pragma("unroll")                                                         \
    for (int kc_ = 0; kc_ < 2; ++kc_) {                                       \
        f16x8 af_[4], bf_[2];                                                 \
        _Pragma("unroll")                                                     \
        for (int m_ = 0; m_ < 4; ++m_) {                                      \
            int row_ = wr * 64 + 16 * m_ + ll;                                \
            af_[m_] = *(const f16x8*)&(AS)[row_ * 64 +                        \
                        (((lg + 4 * kc_) ^ (ll & 7)) * 8)];                   \
        }                                                                     \
        _Pragma("unroll")                                                     \
        for (int n_ = 0; n_ < 2; ++n_) {                                      \
            int col_ = wc * 32 + 16 * n_ + ll;                                \
            bf_[n_] = *(const f16x8*)&(BS)[col_ * 64 +                        \
                        (((lg + 4 * kc_) ^ (ll & 7)) * 8)];                   \
        }                                                                     \
        _Pragma("unroll")                                                     \
        for (int m_ = 0; m_ < 4; ++m_)                                        \
            _Pragma("unroll")                                                 \
            for (int n_ = 0; n_ < 2; ++n_)                                    \
                acc[m_][n_] = __builtin_amdgcn_mfma_f32_16x16x32_f16(         \
                    af_[m_], bf_[n_], acc[m_][n_], 0, 0, 0);                  \
    }                                                                         \
} while (0)

    GSTAGE(As0, Bs0, 0);
    __syncthreads();
#pragma unroll 1
    for (int i = 0; i < 32; i += 2) {
        GSTAGE(As1, Bs1, (i + 1) * 64);
        GCOMP(As0, Bs0);
        __syncthreads();
        if (i + 2 < 32) GSTAGE(As0, Bs0, (i + 2) * 64);
        GCOMP(As1, Bs1);
        __syncthreads();
    }
#undef GSTAGE
#undef GCOMP

    const int orow = row0 + wr * 64 + lg * 4;
    const int ocol = col0 + wc * 32 + ll;
#pragma unroll
    for (int m = 0; m < 4; ++m)
#pragma unroll
        for (int nn = 0; nn < 2; ++nn)
#pragma unroll
            for (int r = 0; r < 4; ++r)
                Cf[(size_t)(orow + 16 * m + r) * CC + ocol + 16 * nn] =
                    acc[m][nn][r];
}

// ---------------------------------------------------------------------------
// MFMA flash attention (swapped roles): triangle-paired blocks, double-buffered
// Q/Vt staging, defer-max rescale.  (unchanged from round 8)
// ---------------------------------------------------------------------------
__global__ __launch_bounds__(256) void attn_mfma(const u16* __restrict__ qkv,
                                                 const u16* __restrict__ vtg,
                                                 u16* __restrict__ attnb) {
    __shared__ __align__(16) u16 Qs0[64 * 128];
    __shared__ __align__(16) u16 Qs1[64 * 128];
    __shared__ __align__(16) u16 Vt0[128 * 64];
    __shared__ __align__(16) u16 Vt1[128 * 64];
    __shared__ __align__(16) u16 Ps[4 * 16 * 72];

    const int t = threadIdx.x, l = t & 63, w = t >> 6;
    const int bh = blockIdx.y;
    const int b = bh >> 4, h = bh & 15, hk = h & 3;
    const int lg = l >> 4, ll = l & 15;

    const u16* qbase = qkv + (size_t)(b * TT) * QKVN + h * 128;
    const u16* vbase = vtg + (size_t)((b * NKV + hk) * 128) * 1024;

    const int rq = 16 * w + (l >> 4);
    const int cq = l & 15;
    const int dv = 32 * w + (l >> 3);
    const int cv = l & 7;

#define STAGE(j0v, Qd, Vd) do {                                               \
    _Pragma("unroll")                                                         \
    for (int e_ = 0; e_ < 4; ++e_) {                                          \
        int r_ = rq + 4 * e_;                                                 \
        GLDS(qbase + (size_t)((j0v) + r_) * QKVN + ((cq ^ (r_ & 7)) * 8),     \
             (Qd) + (16 * w + 4 * e_) * 128);                                 \
    }                                                                         \
    _Pragma("unroll")                                                         \
    for (int e_ = 0; e_ < 4; ++e_) {                                          \
        int d_ = dv + 8 * e_;                                                 \
        GLDS(vbase + (size_t)d_ * 1024 + (j0v) + ((cv ^ (d_ & 7)) * 8),       \
             (Vd) + (32 * w + 8 * e_) * 64);                                  \
    }                                                                         \
} while (0)

#pragma unroll 1
    for (int ph = 0; ph < 2; ++ph) {
        const int it = ph ? (15 - blockIdx.x) : blockIdx.x;
        const int iw = it * 64 + w * 16;

        f16x8 kf[4];
        {
            const u16* kp = qkv + (size_t)(b * TT + iw + ll) * QKVN + KOFF + hk * 128 + lg * 8;
#pragma unroll
            for (int c = 0; c < 4; ++c) kf[c] = *(const f16x8*)(kp + 32 * c);
        }

        f32x4 o[8] = {};
        float mrun[4] = {-1e30f, -1e30f, -1e30f, -1e30f};
        float lrun[4] = {0.f, 0.f, 0.f, 0.f};

        const int nt = it + 1;
        STAGE(0, Qs0, Vt0);
        __syncthreads();

#pragma unroll 1
        for (int jt = 0; jt < nt; ++jt) {
            u16* Qc = (jt & 1) ? Qs1 : Qs0;
            u16* Vc = (jt & 1) ? Vt1 : Vt0;
            if (jt + 1 < nt) {
                u16* Qn = (jt & 1) ? Qs0 : Qs1;
                u16* Vn = (jt & 1) ? Vt0 : Vt1;
                STAGE((jt + 1) * 64, Qn, Vn);
            }

            f32x4 s[4] = {};
#pragma unroll
            for (int kc = 0; kc < 4; ++kc)
#pragma unroll
                for (int n = 0; n < 4; ++n) {
                    f16x8 qf = *(const f16x8*)&Qc[(16 * n + ll) * 128 + (((lg + 4 * kc) ^ (ll & 7)) * 8)];
                    s[n] = __builtin_amdgcn_mfma_f32_16x16x32_f16(kf[kc], qf, s[n], 0, 0, 0);
                }

            if (jt == it) {
#pragma unroll
                for (int n = 0; n < 4; ++n)
#pragma unroll
                    for (int r = 0; r < 4; ++r)
                        s[n][r] = (16 * n + ll <= 16 * w + 4 * lg + r) ? s[n][r] : -1e30f;
            }

            float tml[4];
            bool need = false;
#pragma unroll
            for (int r = 0; r < 4; ++r) {
                float tm = fmaxf(fmaxf(s[0][r], s[1][r]), fmaxf(s[2][r], s[3][r]));
                tml[r] = tm;
                need |= (tm > mrun[r] + 8.0f);
            }
            if (__any(need)) {
#pragma unroll
                for (int r = 0; r < 4; ++r) {
                    float tm = tml[r];
                    tm = fmaxf(tm, __shfl_xor(tm, 1, 16));
                    tm = fmaxf(tm, __shfl_xor(tm, 2, 16));
                    tm = fmaxf(tm, __shfl_xor(tm, 4, 16));
                    tm = fmaxf(tm, __shfl_xor(tm, 8, 16));
                    float mnew = fmaxf(mrun[r], tm);
                    float al = __expf(mrun[r] - mnew);
                    lrun[r] *= al;
                    mrun[r] = mnew;
#pragma unroll
                    for (int n = 0; n < 8; ++n) o[n][r] *= al;
                }
            }
            float p[4][4];
#pragma unroll
            for (int r = 0; r < 4; ++r) {
                float ps = 0.f;
#pragma unroll
                for (int n = 0; n < 4; ++n) { p[n][r] = __expf(s[n][r] - mrun[r]); ps += p[n][r]; }
                lrun[r] += ps;
            }

            u16* pw = Ps + w * (16 * 72);
#pragma unroll
            for (int n = 0; n < 4; ++n)
#pragma unroll
                for (int r = 0; r < 4; ++r)
                    pw[(4 * lg + r) * 72 + ll + 16 * n] = f2h(p[n][r]);
            f16x8 pa0 = *(const f16x8*)&pw[ll * 72 + 8 * lg];
            f16x8 pa1 = *(const f16x8*)&pw[ll * 72 + 8 * lg + 32];

#pragma unroll
            for (int n = 0; n < 8; ++n) {
                f16x8 vf0 = *(const f16x8*)&Vc[(16 * n + ll) * 64 + ((lg ^ (ll & 7)) * 8)];
                o[n] = __builtin_amdgcn_mfma_f32_16x16x32_f16(pa0, vf0, o[n], 0, 0, 0);
                f16x8 vf1 = *(const f16x8*)&Vc[(16 * n + ll) * 64 + (((lg + 4) ^ (ll & 7)) * 8)];
                o[n] = __builtin_amdgcn_mfma_f32_16x16x32_f16(pa1, vf1, o[n], 0, 0, 0);
            }

            __syncthreads();
        }

        u16* dst = attnb + (size_t)(b * TT + iw + 4 * lg) * CC + h * 128 + ll;
#pragma unroll
        for (int r = 0; r < 4; ++r) {
            float L = lrun[r];
            L += __shfl_xor(L, 1, 16);
            L += __shfl_xor(L, 2, 16);
            L += __shfl_xor(L, 4, 16);
            L += __shfl_xor(L, 8, 16);
            float inv = 1.0f / L;
#pragma unroll
            for (int n = 0; n < 8; ++n)
                dst[(size_t)r * CC + 16 * n] = f2h(o[n][r] * inv);
        }
    }
#undef STAGE
}

// ---------------------------------------------------------------------------
extern "C" void kernel_launch(void* const* d_in, const int* in_sizes, int n_in,
                              void* d_out, int out_size, void* d_ws, size_t ws_size,
                              hipStream_t stream) {
    const float* x      = (const float*)d_in[0];
    const float* angles = (const float*)d_in[1];
    const float* wq     = (const float*)d_in[2];
    const float* wk     = (const float*)d_in[3];
    const float* wv     = (const float*)d_in[4];
    const float* wo     = (const float*)d_in[5];
    float* out = (float*)d_out;

    char* ws = (char*)d_ws;
    u16*    Wt1   = (u16*)ws;                         // [0, 12.58M)  qkv weights^T
    u16*    Wt2   = (u16*)(ws + 12582912);            // [12.58M, 20.97M)  wo^T
    float2* cs    = (float2*)(ws + 20971520);         // [20.97M, 21.5M)   sincos table
    u16*    xb    = (u16*)(ws + 21495808);            // [21.5M, 29.9M)
    u16*    qkvb  = (u16*)(ws + 29884416);            // [29.9M, 42.5M)  q,k regions
    u16*    vtg   = (u16*)(ws + 42467328);            // [42.5M, 44.6M)  V^T
    u16*    attnb = (u16*)(ws + 44564480);            // [44.6M, 53.0M)

    // 1. all conversions + sincos table (one launch)
    prep<<<14592, 256, 0, stream>>>(x, wq, wk, wv, wo, angles, xb, Wt1, Wt2, cs);
    // 2. QKV projection, full-K, fused RoPE + V^T epilogue
    gemm_qkv<<<dim3(32, 16), 256, 0, stream>>>(xb, Wt1, qkvb, vtg, cs);
    // 3. attention (paired-balanced, double-buffered)
    attn_mfma<<<dim3(8, BB * NH), 256, 0, stream>>>(qkvb, vtg, attnb);
    // 4. output projection, full-K, 8 waves, fp32 direct out
    gemm_out<<<dim3(16, 16), 512, 0, stream>>>(attnb, Wt2, out);
}